// Round 1
// baseline (5218.678 us; speedup 1.0000x reference)
//
#include <hip/hip_runtime.h>

#define NNODES 4096
#define NB 16
#define NA 256
#define FEATD 64
#define HID 256
#define TEMBD 32
#define NUMT 100
#define NE 131072
#define NL 4

__device__ __forceinline__ float silu_f(float v) { return v / (1.f + __expf(-v)); }

__device__ __forceinline__ float block_sum(float v, float* red, int a) {
    red[a] = v; __syncthreads();
    for (int s = 128; s > 0; s >>= 1) {
        if (a < s) red[a] += red[a + s];
        __syncthreads();
    }
    float r = red[0]; __syncthreads();
    return r;
}

// ---------------------------------------------------------------- prep
__global__ __launch_bounds__(256) void prep_kernel(
    const float* __restrict__ x0, const float* __restrict__ noise,
    const int* __restrict__ t,
    float* __restrict__ noise_c, float* __restrict__ xt, float* __restrict__ temb)
{
    __shared__ float red[256];
    __shared__ float sab_s[2];
    int b = blockIdx.x, a = threadIdx.x;
    int base = (b * NA + a) * 3;

    float nx = noise[base + 0], ny = noise[base + 1], nz = noise[base + 2];
    float mnx = block_sum(nx, red, a) * (1.f / NA);
    float mny = block_sum(ny, red, a) * (1.f / NA);
    float mnz = block_sum(nz, red, a) * (1.f / NA);
    nx -= mnx; ny -= mny; nz -= mnz;
    noise_c[base + 0] = nx; noise_c[base + 1] = ny; noise_c[base + 2] = nz;

    if (a == 0) {
        int tt = t[b];
        float p = 1.f;
        for (int i = 0; i < NUMT; i++) {
            float beta = 1e-4f + (0.02f - 1e-4f) * (float)i / (float)(NUMT - 1);
            if (i <= tt) p *= (1.f - beta);
        }
        sab_s[0] = sqrtf(p);
        sab_s[1] = sqrtf(1.f - p);
    }
    __syncthreads();
    float sab = sab_s[0], s1ab = sab_s[1];

    float xx = sab * x0[base + 0] + s1ab * nx;
    float xy = sab * x0[base + 1] + s1ab * ny;
    float xz = sab * x0[base + 2] + s1ab * nz;
    float mx = block_sum(xx, red, a) * (1.f / NA);
    float my = block_sum(xy, red, a) * (1.f / NA);
    float mz = block_sum(xz, red, a) * (1.f / NA);
    xt[base + 0] = xx - mx; xt[base + 1] = xy - my; xt[base + 2] = xz - mz;

    if (a < TEMBD / 2) {
        float fr = expf(-logf(10000.f) * (float)a / (float)(TEMBD / 2 - 1));
        float ang = (float)t[b] * fr;
        temb[b * TEMBD + a] = sinf(ang);
        temb[b * TEMBD + TEMBD / 2 + a] = cosf(ang);
    }
}

// ---------------------------------------------------------------- h_in = [h | temb]
__global__ __launch_bounds__(256) void build_hin(
    const float* __restrict__ h, const float* __restrict__ temb, float* __restrict__ hin)
{
    int idx = blockIdx.x * 256 + threadIdx.x;   // < 4096*96
    int n = idx / 96;
    int k = idx - n * 96;
    float v;
    if (k < FEATD) v = h[n * FEATD + k];
    else v = temb[(n >> 8) * TEMBD + (k - FEATD)];
    hin[idx] = v;
}

// ---------------------------------------------------------------- generic fp32 GEMM
// C[M,N] = A[M,K] @ B[K,N] (+bias). M%64==0, N%64==0, K%16==0.
__global__ __launch_bounds__(256) void gemm_f32(
    const float* __restrict__ A, const float* __restrict__ B,
    const float* __restrict__ bias, float* __restrict__ C,
    int M, int N, int K)
{
    __shared__ __align__(16) float As[16][68];
    __shared__ __align__(16) float Bs[16][64];
    int bm = blockIdx.x * 64, bn = blockIdx.y * 64;
    int tid = threadIdx.x;
    int tx = tid & 15, ty = tid >> 4;
    float acc[4][4] = {};

    int ka = tid & 15, ma = tid >> 4;
    int nb = tid & 63, kb = tid >> 6;

    for (int k0 = 0; k0 < K; k0 += 16) {
        for (int i = 0; i < 4; i++)
            As[ka][ma + 16 * i] = A[(size_t)(bm + ma + 16 * i) * K + k0 + ka];
        for (int i = 0; i < 4; i++)
            Bs[kb + 4 * i][nb] = B[(size_t)(k0 + kb + 4 * i) * N + bn + nb];
        __syncthreads();
        #pragma unroll
        for (int kk = 0; kk < 16; kk++) {
            float4 av = *(const float4*)&As[kk][ty * 4];
            float4 bv = *(const float4*)&Bs[kk][tx * 4];
            float a4[4] = {av.x, av.y, av.z, av.w};
            float b4[4] = {bv.x, bv.y, bv.z, bv.w};
            #pragma unroll
            for (int i = 0; i < 4; i++)
                #pragma unroll
                for (int j = 0; j < 4; j++)
                    acc[i][j] += a4[i] * b4[j];
        }
        __syncthreads();
    }
    float bv4[4] = {0, 0, 0, 0};
    if (bias) {
        for (int j = 0; j < 4; j++) bv4[j] = bias[bn + tx * 4 + j];
    }
    for (int i = 0; i < 4; i++) {
        int m = bm + ty * 4 + i;
        for (int j = 0; j < 4; j++)
            C[(size_t)m * N + bn + tx * 4 + j] = acc[i][j] + bv4[j];
    }
}

// ---------------------------------------------------------------- fused edge kernel
// 32 edges / block. pre = P1[row]+P2[col]+radial*w512+eb1; m=silu(pre);
// m_ij=silu(m@eW2+eb2); t3=silu(m_ij@cW1+cb1); w=t3.cW2;
// atomics: m_i[row]+=m_ij ; x_agg[row]+=cd*w
#define TE 32
__global__ __launch_bounds__(256) void egnn_edge(
    const float* __restrict__ P1, const float* __restrict__ P2,
    const float* __restrict__ x, const int* __restrict__ row, const int* __restrict__ col,
    const float* __restrict__ w512, const float* __restrict__ eb1,
    const float* __restrict__ eW2, const float* __restrict__ eb2,
    const float* __restrict__ cW1, const float* __restrict__ cb1,
    const float* __restrict__ cW2,
    float* __restrict__ m_i, float* __restrict__ x_agg)
{
    __shared__ __align__(16) float mT[256 * 36];   // [k][e], stride 36
    __shared__ __align__(16) float Wt[16 * 256];   // weight k-tile [kk][c]
    __shared__ float cd[TE * 3];
    __shared__ float radial_s[TE];
    __shared__ int rows_s[TE];
    __shared__ int cols_s[TE];
    __shared__ float wred[TE * 33];

    int tid = threadIdx.x;
    int e0 = blockIdx.x * TE;

    if (tid < TE) {
        int e = e0 + tid;
        int r = row[e], c = col[e];
        rows_s[tid] = r; cols_s[tid] = c;
        float dx = x[r * 3 + 0] - x[c * 3 + 0];
        float dy = x[r * 3 + 1] - x[c * 3 + 1];
        float dz = x[r * 3 + 2] - x[c * 3 + 2];
        cd[tid * 3 + 0] = dx; cd[tid * 3 + 1] = dy; cd[tid * 3 + 2] = dz;
        radial_s[tid] = dx * dx + dy * dy + dz * dz;
    }
    __syncthreads();

    // phase 1: m -> mT[k][e]
    {
        int c = tid;
        float wc = w512[c], bc = eb1[c];
        for (int e = 0; e < TE; e++) {
            float v = P1[(size_t)rows_s[e] * HID + c] + P2[(size_t)cols_s[e] * HID + c]
                      + radial_s[e] * wc + bc;
            mT[c * 36 + e] = silu_f(v);
        }
    }
    __syncthreads();

    int cg = tid & 31, eg = tid >> 5;   // 8 edge-groups x 32 chan-groups
    int ebase = eg * 4, cbase = cg * 8;

    float mij[4][8];
    // phase 2: m_ij = silu(m @ eW2 + eb2)
    {
        float acc[4][8] = {};
        for (int kt = 0; kt < HID; kt += 16) {
            __syncthreads();
            float4* Wt4 = (float4*)Wt;
            const float4* W4 = (const float4*)(eW2 + (size_t)kt * HID);
            for (int i = tid; i < 1024; i += 256) Wt4[i] = W4[i];
            __syncthreads();
            #pragma unroll
            for (int kk = 0; kk < 16; kk++) {
                float4 av = *(const float4*)&mT[(kt + kk) * 36 + ebase];
                float4 b0 = *(const float4*)&Wt[kk * 256 + cbase];
                float4 b1 = *(const float4*)&Wt[kk * 256 + cbase + 4];
                float a4[4] = {av.x, av.y, av.z, av.w};
                float b8[8] = {b0.x, b0.y, b0.z, b0.w, b1.x, b1.y, b1.z, b1.w};
                #pragma unroll
                for (int i = 0; i < 4; i++)
                    #pragma unroll
                    for (int j = 0; j < 8; j++)
                        acc[i][j] += a4[i] * b8[j];
            }
        }
        #pragma unroll
        for (int j = 0; j < 8; j++) {
            float b2 = eb2[cbase + j];
            #pragma unroll
            for (int i = 0; i < 4; i++) mij[i][j] = silu_f(acc[i][j] + b2);
        }
    }
    __syncthreads();   // all phase-2 reads of mT done

    // store m_ij^T back into mT ; atomic segment-sum into m_i
    for (int i = 0; i < 4; i++) {
        int r = rows_s[ebase + i];
        #pragma unroll
        for (int j = 0; j < 8; j++) {
            mT[(cbase + j) * 36 + ebase + i] = mij[i][j];
            atomicAdd(&m_i[(size_t)r * HID + cbase + j], mij[i][j]);
        }
    }
    __syncthreads();

    // phase 3: t3 = silu(m_ij @ cW1 + cb1); w_partial = t3 . cW2
    {
        float acc[4][8] = {};
        for (int kt = 0; kt < HID; kt += 16) {
            __syncthreads();
            float4* Wt4 = (float4*)Wt;
            const float4* W4 = (const float4*)(cW1 + (size_t)kt * HID);
            for (int i = tid; i < 1024; i += 256) Wt4[i] = W4[i];
            __syncthreads();
            #pragma unroll
            for (int kk = 0; kk < 16; kk++) {
                float4 av = *(const float4*)&mT[(kt + kk) * 36 + ebase];
                float4 b0 = *(const float4*)&Wt[kk * 256 + cbase];
                float4 b1 = *(const float4*)&Wt[kk * 256 + cbase + 4];
                float a4[4] = {av.x, av.y, av.z, av.w};
                float b8[8] = {b0.x, b0.y, b0.z, b0.w, b1.x, b1.y, b1.z, b1.w};
                #pragma unroll
                for (int i = 0; i < 4; i++)
                    #pragma unroll
                    for (int j = 0; j < 8; j++)
                        acc[i][j] += a4[i] * b8[j];
            }
        }
        float wp4[4] = {0, 0, 0, 0};
        #pragma unroll
        for (int j = 0; j < 8; j++) {
            float b1 = cb1[cbase + j];
            float c2 = cW2[cbase + j];
            #pragma unroll
            for (int i = 0; i < 4; i++) wp4[i] += silu_f(acc[i][j] + b1) * c2;
        }
        for (int i = 0; i < 4; i++) wred[(ebase + i) * 33 + cg] = wp4[i];
    }
    __syncthreads();

    if (tid < TE) {
        float w = 0.f;
        for (int g = 0; g < 32; g++) w += wred[tid * 33 + g];
        int r = rows_s[tid];
        atomicAdd(&x_agg[r * 3 + 0], cd[tid * 3 + 0] * w);
        atomicAdd(&x_agg[r * 3 + 1], cd[tid * 3 + 1] * w);
        atomicAdd(&x_agg[r * 3 + 2], cd[tid * 3 + 2] * w);
    }
}

// ---------------------------------------------------------------- fused node MLP
// h_new = h + silu([h|m_i]@nW1 + nb1) @ nW2 + nb2 ; 32 nodes/block
__global__ __launch_bounds__(256) void egnn_node(
    const float* __restrict__ hcur, const float* __restrict__ m_i,
    const float* __restrict__ nW1, const float* __restrict__ nb1,
    const float* __restrict__ nW2, const float* __restrict__ nb2,
    float* __restrict__ hnxt)
{
    __shared__ __align__(16) float t1T[256 * 36];
    __shared__ __align__(16) float AsT[16 * 36];
    __shared__ __align__(16) float Wt[16 * 256];

    int tid = threadIdx.x;
    int n0 = blockIdx.x * 32;
    int cg = tid & 31, eg = tid >> 5;
    int nbase = eg * 4, cbase = cg * 8;

    float acc[4][8] = {};
    // phase A: t1 = silu([h|m_i] @ nW1 + nb1), K = 512
    for (int kt = 0; kt < 2 * HID; kt += 16) {
        __syncthreads();
        {
            int n = tid >> 3;            // 0..31
            int kk = (tid & 7) * 2;      // 0..14
            int kglob = kt + kk;
            const float* src = (kglob < HID)
                ? &hcur[(size_t)(n0 + n) * HID + kglob]
                : &m_i[(size_t)(n0 + n) * HID + kglob - HID];
            float2 v = *(const float2*)src;
            AsT[(kk + 0) * 36 + n] = v.x;
            AsT[(kk + 1) * 36 + n] = v.y;
        }
        {
            float4* Wt4 = (float4*)Wt;
            const float4* W4 = (const float4*)(nW1 + (size_t)kt * HID);
            for (int i = tid; i < 1024; i += 256) Wt4[i] = W4[i];
        }
        __syncthreads();
        #pragma unroll
        for (int kk = 0; kk < 16; kk++) {
            float4 av = *(const float4*)&AsT[kk * 36 + nbase];
            float4 b0 = *(const float4*)&Wt[kk * 256 + cbase];
            float4 b1 = *(const float4*)&Wt[kk * 256 + cbase + 4];
            float a4[4] = {av.x, av.y, av.z, av.w};
            float b8[8] = {b0.x, b0.y, b0.z, b0.w, b1.x, b1.y, b1.z, b1.w};
            #pragma unroll
            for (int i = 0; i < 4; i++)
                #pragma unroll
                for (int j = 0; j < 8; j++)
                    acc[i][j] += a4[i] * b8[j];
        }
    }
    __syncthreads();
    #pragma unroll
    for (int j = 0; j < 8; j++) {
        float b1 = nb1[cbase + j];
        #pragma unroll
        for (int i = 0; i < 4; i++)
            t1T[(cbase + j) * 36 + nbase + i] = silu_f(acc[i][j] + b1);
    }

    // phase B: out = t1 @ nW2 + nb2 + h
    float acc2[4][8] = {};
    for (int kt = 0; kt < HID; kt += 16) {
        __syncthreads();
        {
            float4* Wt4 = (float4*)Wt;
            const float4* W4 = (const float4*)(nW2 + (size_t)kt * HID);
            for (int i = tid; i < 1024; i += 256) Wt4[i] = W4[i];
        }
        __syncthreads();
        #pragma unroll
        for (int kk = 0; kk < 16; kk++) {
            float4 av = *(const float4*)&t1T[(kt + kk) * 36 + nbase];
            float4 b0 = *(const float4*)&Wt[kk * 256 + cbase];
            float4 b1 = *(const float4*)&Wt[kk * 256 + cbase + 4];
            float a4[4] = {av.x, av.y, av.z, av.w};
            float b8[8] = {b0.x, b0.y, b0.z, b0.w, b1.x, b1.y, b1.z, b1.w};
            #pragma unroll
            for (int i = 0; i < 4; i++)
                #pragma unroll
                for (int j = 0; j < 8; j++)
                    acc2[i][j] += a4[i] * b8[j];
        }
    }
    #pragma unroll
    for (int j = 0; j < 8; j++) {
        float b2 = nb2[cbase + j];
        #pragma unroll
        for (int i = 0; i < 4; i++) {
            size_t idx = (size_t)(n0 + nbase + i) * HID + cbase + j;
            hnxt[idx] = hcur[idx] + acc2[i][j] + b2;
        }
    }
}

// ---------------------------------------------------------------- x += x_agg
__global__ __launch_bounds__(256) void xupd(float* __restrict__ x, const float* __restrict__ xa)
{
    int i = blockIdx.x * 256 + threadIdx.x;
    if (i < NNODES * 3) x[i] += xa[i];
}

// ---------------------------------------------------------------- loss
__global__ __launch_bounds__(256) void loss_part(
    const float* __restrict__ xfin, const float* __restrict__ xt,
    const float* __restrict__ nc, float* __restrict__ lpart)
{
    __shared__ float red[256];
    int b = blockIdx.x, a = threadIdx.x;
    int base = (b * NA + a) * 3;
    float px = xfin[base + 0] - xt[base + 0];
    float py = xfin[base + 1] - xt[base + 1];
    float pz = xfin[base + 2] - xt[base + 2];
    float mx = block_sum(px, red, a) * (1.f / NA);
    float my = block_sum(py, red, a) * (1.f / NA);
    float mz = block_sum(pz, red, a) * (1.f / NA);
    px -= mx; py -= my; pz -= mz;
    float dx = px - nc[base + 0], dy = py - nc[base + 1], dz = pz - nc[base + 2];
    float s = block_sum(dx * dx + dy * dy + dz * dz, red, a);
    if (a == 0) lpart[b] = s;
}

__global__ void loss_final(const float* __restrict__ lpart, float* __restrict__ out)
{
    if (threadIdx.x == 0) {
        float s = 0.f;
        for (int i = 0; i < NB; i++) s += lpart[i];
        out[0] = s / (float)(NNODES * 3);
    }
}

// ---------------------------------------------------------------- launch
extern "C" void kernel_launch(void* const* d_in, const int* in_sizes, int n_in,
                              void* d_out, int out_size, void* d_ws, size_t ws_size,
                              hipStream_t stream)
{
    (void)in_sizes; (void)n_in; (void)out_size; (void)ws_size;
    const float* h     = (const float*)d_in[0];
    const float* x0    = (const float*)d_in[1];
    const float* noise = (const float*)d_in[2];
    const int*   t     = (const int*)d_in[3];
    const int*   row   = (const int*)d_in[4];
    const int*   col   = (const int*)d_in[5];
    const float* W_emb = (const float*)d_in[6];
    const float* b_emb = (const float*)d_in[7];
    const float* eW1   = (const float*)d_in[8];
    const float* eb1   = (const float*)d_in[9];
    const float* eW2   = (const float*)d_in[10];
    const float* eb2   = (const float*)d_in[11];
    const float* cW1   = (const float*)d_in[12];
    const float* cb1   = (const float*)d_in[13];
    const float* cW2   = (const float*)d_in[14];
    const float* nW1   = (const float*)d_in[15];
    const float* nb1   = (const float*)d_in[16];
    const float* nW2   = (const float*)d_in[17];
    const float* nb2   = (const float*)d_in[18];

    float* ws = (float*)d_ws;
    size_t o = 0;
    float* temb    = ws + o; o += NB * TEMBD;          // 512
    float* noise_c = ws + o; o += NNODES * 3;          // 12288
    float* xt      = ws + o; o += NNODES * 3;
    float* hin     = ws + o; o += (size_t)NNODES * 96;
    float* hh      = ws + o; o += (size_t)NNODES * HID;
    float* hh2     = ws + o; o += (size_t)NNODES * HID;
    float* P1      = ws + o; o += (size_t)NNODES * HID;
    float* P2      = ws + o; o += (size_t)NNODES * HID;
    float* m_i     = ws + o; o += (size_t)NNODES * HID;
    float* x_cur   = ws + o; o += NNODES * 3;
    float* x_agg   = ws + o; o += NNODES * 3;
    float* lpart   = ws + o; o += NB;

    prep_kernel<<<NB, 256, 0, stream>>>(x0, noise, t, noise_c, xt, temb);
    build_hin<<<(NNODES * 96) / 256, 256, 0, stream>>>(h, temb, hin);
    gemm_f32<<<dim3(NNODES / 64, HID / 64), 256, 0, stream>>>(hin, W_emb, b_emb, hh, NNODES, HID, 96);
    hipMemcpyAsync(x_cur, xt, (size_t)NNODES * 3 * sizeof(float), hipMemcpyDeviceToDevice, stream);

    float* hc = hh;
    float* hn = hh2;
    for (int l = 0; l < NL; l++) {
        const float* eW1l = eW1 + (size_t)l * 513 * HID;
        gemm_f32<<<dim3(NNODES / 64, HID / 64), 256, 0, stream>>>(hc, eW1l, nullptr, P1, NNODES, HID, HID);
        gemm_f32<<<dim3(NNODES / 64, HID / 64), 256, 0, stream>>>(hc, eW1l + 256 * HID, nullptr, P2, NNODES, HID, HID);
        hipMemsetAsync(m_i, 0, (size_t)NNODES * HID * sizeof(float), stream);
        hipMemsetAsync(x_agg, 0, (size_t)NNODES * 3 * sizeof(float), stream);
        egnn_edge<<<NE / TE, 256, 0, stream>>>(
            P1, P2, x_cur, row, col,
            eW1l + 512 * HID, eb1 + (size_t)l * HID,
            eW2 + (size_t)l * HID * HID, eb2 + (size_t)l * HID,
            cW1 + (size_t)l * HID * HID, cb1 + (size_t)l * HID,
            cW2 + (size_t)l * HID,
            m_i, x_agg);
        if (l < NL - 1) {
            egnn_node<<<NNODES / 32, 256, 0, stream>>>(
                hc, m_i,
                nW1 + (size_t)l * 2 * HID * HID, nb1 + (size_t)l * HID,
                nW2 + (size_t)l * HID * HID, nb2 + (size_t)l * HID,
                hn);
            float* tmp = hc; hc = hn; hn = tmp;
        }
        xupd<<<(NNODES * 3) / 256, 256, 0, stream>>>(x_cur, x_agg);
    }

    loss_part<<<NB, 256, 0, stream>>>(x_cur, xt, noise_c, lpart);
    loss_final<<<1, 64, 0, stream>>>(lpart, (float*)d_out);
}

// Round 2
// 1183.543 us; speedup vs baseline: 4.4094x; 4.4094x over previous
//
#include <hip/hip_runtime.h>

#define NB 16
#define NA 256
#define NNODES 4096
#define FEATD 64
#define HID 256
#define TEMBD 32
#define NUMT 100
#define NE 131072
#define NL 4

typedef __attribute__((ext_vector_type(8))) short short8;
typedef __attribute__((ext_vector_type(4))) float f32x4;

__device__ __forceinline__ float silu_f(float v) { return v / (1.f + __expf(-v)); }

__device__ __forceinline__ short f2bf(float f) {
    union { float f; unsigned u; } v; v.f = f;
    unsigned r = (v.u + 0x7fffu + ((v.u >> 16) & 1u)) >> 16;
    return (short)r;
}
__device__ __forceinline__ float bf2f(short s) {
    union { float f; unsigned u; } v; v.u = ((unsigned)(unsigned short)s) << 16;
    return v.f;
}

__device__ __forceinline__ float block_sum(float v, float* red, int a) {
    red[a] = v; __syncthreads();
    for (int s = 128; s > 0; s >>= 1) {
        if (a < s) red[a] += red[a + s];
        __syncthreads();
    }
    float r = red[0]; __syncthreads();
    return r;
}

// ---------------------------------------------------------------- prep
__global__ __launch_bounds__(256) void prep_kernel(
    const float* __restrict__ x0, const float* __restrict__ noise,
    const int* __restrict__ t,
    float* __restrict__ noise_c, float* __restrict__ xt, float* __restrict__ temb)
{
    __shared__ float red[256];
    __shared__ float sab_s[2];
    int b = blockIdx.x, a = threadIdx.x;
    int base = (b * NA + a) * 3;

    float nx = noise[base + 0], ny = noise[base + 1], nz = noise[base + 2];
    float mnx = block_sum(nx, red, a) * (1.f / NA);
    float mny = block_sum(ny, red, a) * (1.f / NA);
    float mnz = block_sum(nz, red, a) * (1.f / NA);
    nx -= mnx; ny -= mny; nz -= mnz;
    noise_c[base + 0] = nx; noise_c[base + 1] = ny; noise_c[base + 2] = nz;

    if (a == 0) {
        int tt = t[b];
        float p = 1.f;
        for (int i = 0; i < NUMT; i++) {
            float beta = 1e-4f + (0.02f - 1e-4f) * (float)i / (float)(NUMT - 1);
            if (i <= tt) p *= (1.f - beta);
        }
        sab_s[0] = sqrtf(p);
        sab_s[1] = sqrtf(1.f - p);
    }
    __syncthreads();
    float sab = sab_s[0], s1ab = sab_s[1];

    float xx = sab * x0[base + 0] + s1ab * nx;
    float xy = sab * x0[base + 1] + s1ab * ny;
    float xz = sab * x0[base + 2] + s1ab * nz;
    float mx = block_sum(xx, red, a) * (1.f / NA);
    float my = block_sum(xy, red, a) * (1.f / NA);
    float mz = block_sum(xz, red, a) * (1.f / NA);
    xt[base + 0] = xx - mx; xt[base + 1] = xy - my; xt[base + 2] = xz - mz;

    if (a < TEMBD / 2) {
        float fr = expf(-logf(10000.f) * (float)a / (float)(TEMBD / 2 - 1));
        float ang = (float)t[b] * fr;
        temb[b * TEMBD + a] = sinf(ang);
        temb[b * TEMBD + TEMBD / 2 + a] = cosf(ang);
    }
}

// ---------------------------------------------------------------- CSR build
__global__ __launch_bounds__(256) void csr_hist(const int* __restrict__ row, int* __restrict__ deg)
{
    int i = blockIdx.x * 256 + threadIdx.x;
    if (i < NE) atomicAdd(&deg[row[i]], 1);
}

__global__ __launch_bounds__(256) void csr_scan(const int* __restrict__ deg, int* __restrict__ cursor)
{
    __shared__ int s[256];
    int t = threadIdx.x;
    int base = t * 16;
    int loc[16];
    int sum = 0;
    for (int i = 0; i < 16; i++) { loc[i] = sum; sum += deg[base + i]; }
    s[t] = sum; __syncthreads();
    for (int off = 1; off < 256; off <<= 1) {
        int v = (t >= off) ? s[t - off] : 0;
        __syncthreads();
        s[t] += v;
        __syncthreads();
    }
    int excl = (t == 0) ? 0 : s[t - 1];
    for (int i = 0; i < 16; i++) cursor[base + i] = excl + loc[i];
}

__global__ __launch_bounds__(256) void csr_scatter(
    const int* __restrict__ row, const int* __restrict__ col,
    int* __restrict__ cursor, int* __restrict__ prow, int* __restrict__ pcol)
{
    int i = blockIdx.x * 256 + threadIdx.x;
    if (i < NE) {
        int r = row[i];
        int p = atomicAdd(&cursor[r], 1);
        prow[p] = r;
        pcol[p] = col[i];
    }
}

// ---------------------------------------------------------------- weight convert+k-tile
// dst layout per weight: [kt][n(256)][kk(32)] bf16, kt = K/32 tiles
#define WOFF_EMB 0
#define WOFF_L(l) (24576 + (l) * 458752)
#define WOFF_A 0
#define WOFF_B 65536
#define WOFF_E2 131072
#define WOFF_C1 196608
#define WOFF_N1 262144
#define WOFF_N2 393216
#define W_TOTAL (24576 + 4 * 458752)

__global__ __launch_bounds__(256) void convert_weights(
    const float* __restrict__ W_emb, const float* __restrict__ eW1,
    const float* __restrict__ eW2, const float* __restrict__ cW1,
    const float* __restrict__ nW1, const float* __restrict__ nW2,
    short* __restrict__ wb)
{
    int idx = blockIdx.x * 256 + threadIdx.x;
    if (idx >= W_TOTAL) return;
    if (idx < 24576) {
        int k = idx >> 8, n = idx & 255;
        wb[WOFF_EMB + ((k >> 5) << 13) + (n << 5) + (k & 31)] = f2bf(W_emb[idx]);
        return;
    }
    int r = idx - 24576;
    int l = r / 458752;
    int o = r - l * 458752;
    const float* src;
    int dst;
    if (o < 65536)       {              src = eW1 + (size_t)l * 513 * 256 + o;          dst = WOFF_L(l) + WOFF_A; }
    else if (o < 131072) { o -= 65536;  src = eW1 + (size_t)l * 513 * 256 + 65536 + o;  dst = WOFF_L(l) + WOFF_B; }
    else if (o < 196608) { o -= 131072; src = eW2 + (size_t)l * 65536 + o;              dst = WOFF_L(l) + WOFF_E2; }
    else if (o < 262144) { o -= 196608; src = cW1 + (size_t)l * 65536 + o;              dst = WOFF_L(l) + WOFF_C1; }
    else if (o < 393216) { o -= 262144; src = nW1 + (size_t)l * 131072 + o;             dst = WOFF_L(l) + WOFF_N1; }
    else                 { o -= 393216; src = nW2 + (size_t)l * 65536 + o;              dst = WOFF_L(l) + WOFF_N2; }
    int k = o >> 8, n = o & 255;
    wb[dst + ((k >> 5) << 13) + (n << 5) + (k & 31)] = f2bf(*src);
}

// ---------------------------------------------------------------- h_in = [h | temb] (bf16)
__global__ __launch_bounds__(256) void build_hin(
    const float* __restrict__ h, const float* __restrict__ temb, short* __restrict__ hin)
{
    int idx = blockIdx.x * 256 + threadIdx.x;   // < 4096*96
    int n = idx / 96;
    int k = idx - n * 96;
    float v = (k < FEATD) ? h[n * FEATD + k] : temb[(n >> 8) * TEMBD + (k - FEATD)];
    hin[idx] = f2bf(v);
}

// ---------------------------------------------------------------- concat [h | m_i] bf16
__global__ __launch_bounds__(256) void concat_hm(
    const short* __restrict__ hc, const float* __restrict__ m_i, short* __restrict__ hm)
{
    int idx = blockIdx.x * 256 + threadIdx.x;   // < 4096*512
    int n = idx >> 9, k = idx & 511;
    hm[idx] = (k < 256) ? hc[n * 256 + k] : f2bf(m_i[n * 256 + k - 256]);
}

// ---------------------------------------------------------------- generic bf16 MFMA GEMM
// out[M,256] = act(A[M,K] @ W + bias) (+res). W in k-tiled layout. grid.x = M/64.
__global__ __launch_bounds__(256) void gemm_mfma(
    const short* __restrict__ A, const short* __restrict__ Wt,
    const float* __restrict__ bias, const short* __restrict__ res,
    short* __restrict__ out, int K, int act)
{
    __shared__ short a_lds[64 * 40];
    __shared__ short w_lds[256 * 40];
    int tid = threadIdx.x;
    int l = tid & 63, wv = tid >> 6;
    int lr = l & 15, q = l >> 4;
    int m0 = blockIdx.x * 64;
    int ksteps = K >> 5;

    f32x4 acc[4][4];
    #pragma unroll
    for (int i = 0; i < 4; i++)
        #pragma unroll
        for (int j = 0; j < 4; j++) acc[i][j] = (f32x4){0.f, 0.f, 0.f, 0.f};

    for (int kt = 0; kt < ksteps; kt++) {
        {
            int rrow = tid >> 2, ch = tid & 3;
            *(short8*)&a_lds[rrow * 40 + ch * 8] =
                *(const short8*)&A[(size_t)(m0 + rrow) * K + kt * 32 + ch * 8];
        }
        #pragma unroll
        for (int it = 0; it < 4; it++) {
            int flat = it * 2048 + tid * 8;
            *(short8*)&w_lds[(flat >> 5) * 40 + (flat & 31)] =
                *(const short8*)&Wt[kt * 8192 + flat];
        }
        __syncthreads();
        short8 fa[4], fb[4];
        #pragma unroll
        for (int mt = 0; mt < 4; mt++)
            fa[mt] = *(const short8*)&a_lds[(mt * 16 + lr) * 40 + q * 8];
        #pragma unroll
        for (int nt = 0; nt < 4; nt++)
            fb[nt] = *(const short8*)&w_lds[(wv * 64 + nt * 16 + lr) * 40 + q * 8];
        #pragma unroll
        for (int mt = 0; mt < 4; mt++)
            #pragma unroll
            for (int nt = 0; nt < 4; nt++)
                acc[mt][nt] = __builtin_amdgcn_mfma_f32_16x16x32_bf16(fa[mt], fb[nt], acc[mt][nt], 0, 0, 0);
        __syncthreads();
    }

    #pragma unroll
    for (int nt = 0; nt < 4; nt++) {
        int ccol = wv * 64 + nt * 16 + lr;
        float bv = bias ? bias[ccol] : 0.f;
        #pragma unroll
        for (int mt = 0; mt < 4; mt++) {
            #pragma unroll
            for (int rg = 0; rg < 4; rg++) {
                int rrow = m0 + mt * 16 + q * 4 + rg;
                float v = acc[mt][nt][rg] + bv;
                if (act) v = silu_f(v);
                size_t oi = (size_t)rrow * 256 + ccol;
                if (res) v += bf2f(res[oi]);
                out[oi] = f2bf(v);
            }
        }
    }
}

// ---------------------------------------------------------------- fused edge kernel (MFMA)
// 64 CSR-sorted edges/block. m = silu(P1[r]+P2[c]+radial*w512+eb1) (bf16 LDS)
// m_ij = silu(m@eW2+eb2) -> overwrites m in LDS; run-flush into m_i
// t3 = silu(m_ij@cW1+cb1); w = t3.cW2; x_agg[r] += cd*w
__global__ __launch_bounds__(256) void egnn_edge_mfma(
    const short* __restrict__ P1, const short* __restrict__ P2,
    const float* __restrict__ x,
    const int* __restrict__ prow, const int* __restrict__ pcol,
    const float* __restrict__ w512, const float* __restrict__ eb1,
    const short* __restrict__ wtE2, const float* __restrict__ eb2,
    const short* __restrict__ wtC1, const float* __restrict__ cb1,
    const float* __restrict__ cW2,
    float* __restrict__ m_i, float* __restrict__ x_agg)
{
    __shared__ short m_lds[64 * 264];
    __shared__ short w_lds[256 * 40];
    __shared__ float cd_s[64][3];
    __shared__ float radial_s[64];
    __shared__ int prow_s[64];
    __shared__ int pcol_s[64];
    __shared__ float wred[4 * 64 * 17];

    int tid = threadIdx.x;
    int e0 = blockIdx.x * 64;
    int l = tid & 63, wv = tid >> 6;
    int lr = l & 15, q = l >> 4;

    if (tid < 64) {
        int r = prow[e0 + tid], c = pcol[e0 + tid];
        prow_s[tid] = r; pcol_s[tid] = c;
        float dx = x[r * 3 + 0] - x[c * 3 + 0];
        float dy = x[r * 3 + 1] - x[c * 3 + 1];
        float dz = x[r * 3 + 2] - x[c * 3 + 2];
        cd_s[tid][0] = dx; cd_s[tid][1] = dy; cd_s[tid][2] = dz;
        radial_s[tid] = dx * dx + dy * dy + dz * dz;
    }
    __syncthreads();

    // ---- phase 1: m[64][256] bf16 in LDS (stride 264)
    {
        int c = tid;
        float wc = w512[c], bc = eb1[c];
        for (int e = 0; e < 64; e++) {
            float v = bf2f(P1[(size_t)prow_s[e] * 256 + c])
                    + bf2f(P2[(size_t)pcol_s[e] * 256 + c])
                    + radial_s[e] * wc + bc;
            m_lds[e * 264 + c] = f2bf(silu_f(v));
        }
    }

    f32x4 acc[4][4];
    // ---- phase 2: m @ eW2
    #pragma unroll
    for (int i = 0; i < 4; i++)
        #pragma unroll
        for (int j = 0; j < 4; j++) acc[i][j] = (f32x4){0.f, 0.f, 0.f, 0.f};
    for (int kt = 0; kt < 8; kt++) {
        #pragma unroll
        for (int it = 0; it < 4; it++) {
            int flat = it * 2048 + tid * 8;
            *(short8*)&w_lds[(flat >> 5) * 40 + (flat & 31)] =
                *(const short8*)&wtE2[kt * 8192 + flat];
        }
        __syncthreads();
        short8 fa[4], fb[4];
        #pragma unroll
        for (int mt = 0; mt < 4; mt++)
            fa[mt] = *(const short8*)&m_lds[(mt * 16 + lr) * 264 + kt * 32 + q * 8];
        #pragma unroll
        for (int nt = 0; nt < 4; nt++)
            fb[nt] = *(const short8*)&w_lds[(wv * 64 + nt * 16 + lr) * 40 + q * 8];
        #pragma unroll
        for (int mt = 0; mt < 4; mt++)
            #pragma unroll
            for (int nt = 0; nt < 4; nt++)
                acc[mt][nt] = __builtin_amdgcn_mfma_f32_16x16x32_bf16(fa[mt], fb[nt], acc[mt][nt], 0, 0, 0);
        __syncthreads();
    }
    // epilogue 2: m_ij overwrites m_lds
    #pragma unroll
    for (int nt = 0; nt < 4; nt++) {
        int ccol = wv * 64 + nt * 16 + lr;
        float b2 = eb2[ccol];
        #pragma unroll
        for (int mt = 0; mt < 4; mt++)
            #pragma unroll
            for (int rg = 0; rg < 4; rg++) {
                int e = mt * 16 + q * 4 + rg;
                m_lds[e * 264 + ccol] = f2bf(silu_f(acc[mt][nt][rg] + b2));
            }
    }
    __syncthreads();

    // ---- m_i run-flush (CSR-sorted rows -> few atomics)
    {
        int c = tid;
        float a = 0.f;
        for (int e = 0; e < 64; e++) {
            a += bf2f(m_lds[e * 264 + c]);
            if (e == 63 || prow_s[e + 1] != prow_s[e]) {
                atomicAdd(&m_i[(size_t)prow_s[e] * 256 + c], a);
                a = 0.f;
            }
        }
    }
    __syncthreads();

    // ---- phase 3: m_ij @ cW1
    #pragma unroll
    for (int i = 0; i < 4; i++)
        #pragma unroll
        for (int j = 0; j < 4; j++) acc[i][j] = (f32x4){0.f, 0.f, 0.f, 0.f};
    for (int kt = 0; kt < 8; kt++) {
        #pragma unroll
        for (int it = 0; it < 4; it++) {
            int flat = it * 2048 + tid * 8;
            *(short8*)&w_lds[(flat >> 5) * 40 + (flat & 31)] =
                *(const short8*)&wtC1[kt * 8192 + flat];
        }
        __syncthreads();
        short8 fa[4], fb[4];
        #pragma unroll
        for (int mt = 0; mt < 4; mt++)
            fa[mt] = *(const short8*)&m_lds[(mt * 16 + lr) * 264 + kt * 32 + q * 8];
        #pragma unroll
        for (int nt = 0; nt < 4; nt++)
            fb[nt] = *(const short8*)&w_lds[(wv * 64 + nt * 16 + lr) * 40 + q * 8];
        #pragma unroll
        for (int mt = 0; mt < 4; mt++)
            #pragma unroll
            for (int nt = 0; nt < 4; nt++)
                acc[mt][nt] = __builtin_amdgcn_mfma_f32_16x16x32_bf16(fa[mt], fb[nt], acc[mt][nt], 0, 0, 0);
        __syncthreads();
    }
    // epilogue 3: w partials
    float wp[4][4];
    #pragma unroll
    for (int i = 0; i < 4; i++)
        #pragma unroll
        for (int j = 0; j < 4; j++) wp[i][j] = 0.f;
    #pragma unroll
    for (int nt = 0; nt < 4; nt++) {
        int ccol = wv * 64 + nt * 16 + lr;
        float b1 = cb1[ccol];
        float c2 = cW2[ccol];
        #pragma unroll
        for (int mt = 0; mt < 4; mt++)
            #pragma unroll
            for (int rg = 0; rg < 4; rg++)
                wp[mt][rg] += silu_f(acc[mt][nt][rg] + b1) * c2;
    }
    #pragma unroll
    for (int mt = 0; mt < 4; mt++)
        #pragma unroll
        for (int rg = 0; rg < 4; rg++) {
            int e = mt * 16 + q * 4 + rg;
            wred[(wv * 64 + e) * 17 + lr] = wp[mt][rg];
        }
    __syncthreads();

    if (tid < 64) {
        float w = 0.f;
        for (int wv2 = 0; wv2 < 4; wv2++)
            for (int i = 0; i < 16; i++)
                w += wred[(wv2 * 64 + tid) * 17 + i];
        int r = prow_s[tid];
        atomicAdd(&x_agg[r * 3 + 0], cd_s[tid][0] * w);
        atomicAdd(&x_agg[r * 3 + 1], cd_s[tid][1] * w);
        atomicAdd(&x_agg[r * 3 + 2], cd_s[tid][2] * w);
    }
}

// ---------------------------------------------------------------- x += x_agg
__global__ __launch_bounds__(256) void xupd(float* __restrict__ x, const float* __restrict__ xa)
{
    int i = blockIdx.x * 256 + threadIdx.x;
    if (i < NNODES * 3) x[i] += xa[i];
}

// ---------------------------------------------------------------- loss
__global__ __launch_bounds__(256) void loss_part(
    const float* __restrict__ xfin, const float* __restrict__ xt,
    const float* __restrict__ nc, float* __restrict__ lpart)
{
    __shared__ float red[256];
    int b = blockIdx.x, a = threadIdx.x;
    int base = (b * NA + a) * 3;
    float px = xfin[base + 0] - xt[base + 0];
    float py = xfin[base + 1] - xt[base + 1];
    float pz = xfin[base + 2] - xt[base + 2];
    float mx = block_sum(px, red, a) * (1.f / NA);
    float my = block_sum(py, red, a) * (1.f / NA);
    float mz = block_sum(pz, red, a) * (1.f / NA);
    px -= mx; py -= my; pz -= mz;
    float dx = px - nc[base + 0], dy = py - nc[base + 1], dz = pz - nc[base + 2];
    float s = block_sum(dx * dx + dy * dy + dz * dz, red, a);
    if (a == 0) lpart[b] = s;
}

__global__ void loss_final(const float* __restrict__ lpart, float* __restrict__ out)
{
    if (threadIdx.x == 0) {
        float s = 0.f;
        for (int i = 0; i < NB; i++) s += lpart[i];
        out[0] = s / (float)(NNODES * 3);
    }
}

// ---------------------------------------------------------------- launch
extern "C" void kernel_launch(void* const* d_in, const int* in_sizes, int n_in,
                              void* d_out, int out_size, void* d_ws, size_t ws_size,
                              hipStream_t stream)
{
    (void)in_sizes; (void)n_in; (void)out_size; (void)ws_size;
    const float* h     = (const float*)d_in[0];
    const float* x0    = (const float*)d_in[1];
    const float* noise = (const float*)d_in[2];
    const int*   t     = (const int*)d_in[3];
    const int*   row   = (const int*)d_in[4];
    const int*   col   = (const int*)d_in[5];
    const float* W_emb = (const float*)d_in[6];
    const float* b_emb = (const float*)d_in[7];
    const float* eW1   = (const float*)d_in[8];
    const float* eb1   = (const float*)d_in[9];
    const float* eW2   = (const float*)d_in[10];
    const float* eb2   = (const float*)d_in[11];
    const float* cW1   = (const float*)d_in[12];
    const float* cb1   = (const float*)d_in[13];
    const float* cW2   = (const float*)d_in[14];
    const float* nW1   = (const float*)d_in[15];
    const float* nb1   = (const float*)d_in[16];
    const float* nW2   = (const float*)d_in[17];
    const float* nb2   = (const float*)d_in[18];

    // ---- workspace layout
    float* f = (float*)d_ws;
    size_t fo = 0;
    float* temb    = f + fo; fo += NB * TEMBD;       // 512
    float* noise_c = f + fo; fo += NNODES * 3;
    float* xt      = f + fo; fo += NNODES * 3;
    float* x_cur   = f + fo; fo += NNODES * 3;
    float* x_agg   = f + fo; fo += NNODES * 3;
    float* m_i     = f + fo; fo += (size_t)NNODES * HID;   // 4MB
    float* lpart   = f + fo; fo += NB;

    int* iw = (int*)(f + fo);
    size_t io = 0;
    int* deg    = iw + io; io += NNODES;
    int* cursor = iw + io; io += NNODES;
    int* prow   = iw + io; io += NE;
    int* pcol   = iw + io; io += NE;

    size_t sbase_bytes = ((((char*)(iw + io)) - (char*)d_ws) + 15) & ~(size_t)15;
    short* sb = (short*)((char*)d_ws + sbase_bytes);
    short* wb  = sb;                          // W_TOTAL = 1,859,584 bf16
    size_t so = W_TOTAL;
    short* hin = sb + so; so += (size_t)NNODES * 96;
    short* hh  = sb + so; so += (size_t)NNODES * HID;
    short* hh2 = sb + so; so += (size_t)NNODES * HID;
    short* P1s = sb + so; so += (size_t)NNODES * HID;
    short* P2s = sb + so; so += (size_t)NNODES * HID;
    short* hm  = sb + so; so += (size_t)NNODES * 2 * HID;
    short* t1  = sb + so; so += (size_t)NNODES * HID;

    // ---- prep + CSR + weights
    prep_kernel<<<NB, 256, 0, stream>>>(x0, noise, t, noise_c, xt, temb);
    hipMemsetAsync(deg, 0, NNODES * sizeof(int), stream);
    csr_hist<<<NE / 256, 256, 0, stream>>>(row, deg);
    csr_scan<<<1, 256, 0, stream>>>(deg, cursor);
    csr_scatter<<<NE / 256, 256, 0, stream>>>(row, col, cursor, prow, pcol);
    convert_weights<<<W_TOTAL / 256, 256, 0, stream>>>(W_emb, eW1, eW2, cW1, nW1, nW2, wb);

    build_hin<<<(NNODES * 96) / 256, 256, 0, stream>>>(h, temb, hin);
    gemm_mfma<<<NNODES / 64, 256, 0, stream>>>(hin, wb + WOFF_EMB, b_emb, nullptr, hh, 96, 0);
    hipMemcpyAsync(x_cur, xt, (size_t)NNODES * 3 * sizeof(float), hipMemcpyDeviceToDevice, stream);

    short* hc = hh;
    short* hn = hh2;
    for (int l = 0; l < NL; l++) {
        const short* wl = wb + WOFF_L(l);
        gemm_mfma<<<NNODES / 64, 256, 0, stream>>>(hc, wl + WOFF_A, nullptr, nullptr, P1s, 256, 0);
        gemm_mfma<<<NNODES / 64, 256, 0, stream>>>(hc, wl + WOFF_B, nullptr, nullptr, P2s, 256, 0);
        hipMemsetAsync(m_i, 0, (size_t)NNODES * HID * sizeof(float), stream);
        hipMemsetAsync(x_agg, 0, (size_t)NNODES * 3 * sizeof(float), stream);
        egnn_edge_mfma<<<NE / 64, 256, 0, stream>>>(
            P1s, P2s, x_cur, prow, pcol,
            eW1 + (size_t)l * 513 * 256 + 512 * 256, eb1 + (size_t)l * HID,
            wl + WOFF_E2, eb2 + (size_t)l * HID,
            wl + WOFF_C1, cb1 + (size_t)l * HID,
            cW2 + (size_t)l * HID,
            m_i, x_agg);
        if (l < NL - 1) {
            concat_hm<<<(NNODES * 512) / 256, 256, 0, stream>>>(hc, m_i, hm);
            gemm_mfma<<<NNODES / 64, 256, 0, stream>>>(hm, wl + WOFF_N1, nb1 + (size_t)l * HID, nullptr, t1, 512, 1);
            gemm_mfma<<<NNODES / 64, 256, 0, stream>>>(t1, wl + WOFF_N2, nb2 + (size_t)l * HID, hc, hn, 256, 0);
            short* tmp = hc; hc = hn; hn = tmp;
        }
        xupd<<<(NNODES * 3 + 255) / 256, 256, 0, stream>>>(x_cur, x_agg);
    }

    loss_part<<<NB, 256, 0, stream>>>(x_cur, xt, noise_c, lpart);
    loss_final<<<1, 64, 0, stream>>>(lpart, (float*)d_out);
}

// Round 3
// 1006.301 us; speedup vs baseline: 5.1860x; 1.1761x over previous
//
#include <hip/hip_runtime.h>

#define NB 16
#define NA 256
#define NNODES 4096
#define FEATD 64
#define HID 256
#define TEMBD 32
#define NUMT 100
#define NE 131072
#define NL 4

typedef __attribute__((ext_vector_type(8))) short short8;
typedef __attribute__((ext_vector_type(4))) float f32x4;

__device__ __forceinline__ float silu_f(float v) { return v / (1.f + __expf(-v)); }

__device__ __forceinline__ short f2bf(float f) {
    union { float f; unsigned u; } v; v.f = f;
    unsigned r = (v.u + 0x7fffu + ((v.u >> 16) & 1u)) >> 16;
    return (short)r;
}
__device__ __forceinline__ float bf2f(short s) {
    union { float f; unsigned u; } v; v.u = ((unsigned)(unsigned short)s) << 16;
    return v.f;
}

__device__ __forceinline__ float block_sum(float v, float* red, int a) {
    red[a] = v; __syncthreads();
    for (int s = 128; s > 0; s >>= 1) {
        if (a < s) red[a] += red[a + s];
        __syncthreads();
    }
    float r = red[0]; __syncthreads();
    return r;
}

// m_lds addressing: 72-short sub-rows (36 words == 4 mod 32) kill the
// col-chunk bank aliasing; row stride 296 shorts (148 words == 20 mod 32).
__device__ __forceinline__ int mofs(int e, int c) {
    return e * 296 + (c >> 6) * 72 + (c & 63);
}

// ---------------------------------------------------------------- prep
__global__ __launch_bounds__(256) void prep_kernel(
    const float* __restrict__ x0, const float* __restrict__ noise,
    const int* __restrict__ t,
    float* __restrict__ noise_c, float* __restrict__ xt, float* __restrict__ temb)
{
    __shared__ float red[256];
    __shared__ float sab_s[2];
    int b = blockIdx.x, a = threadIdx.x;
    int base = (b * NA + a) * 3;

    float nx = noise[base + 0], ny = noise[base + 1], nz = noise[base + 2];
    float mnx = block_sum(nx, red, a) * (1.f / NA);
    float mny = block_sum(ny, red, a) * (1.f / NA);
    float mnz = block_sum(nz, red, a) * (1.f / NA);
    nx -= mnx; ny -= mny; nz -= mnz;
    noise_c[base + 0] = nx; noise_c[base + 1] = ny; noise_c[base + 2] = nz;

    if (a == 0) {
        int tt = t[b];
        float p = 1.f;
        for (int i = 0; i < NUMT; i++) {
            float beta = 1e-4f + (0.02f - 1e-4f) * (float)i / (float)(NUMT - 1);
            if (i <= tt) p *= (1.f - beta);
        }
        sab_s[0] = sqrtf(p);
        sab_s[1] = sqrtf(1.f - p);
    }
    __syncthreads();
    float sab = sab_s[0], s1ab = sab_s[1];

    float xx = sab * x0[base + 0] + s1ab * nx;
    float xy = sab * x0[base + 1] + s1ab * ny;
    float xz = sab * x0[base + 2] + s1ab * nz;
    float mx = block_sum(xx, red, a) * (1.f / NA);
    float my = block_sum(xy, red, a) * (1.f / NA);
    float mz = block_sum(xz, red, a) * (1.f / NA);
    xt[base + 0] = xx - mx; xt[base + 1] = xy - my; xt[base + 2] = xz - mz;

    if (a < TEMBD / 2) {
        float fr = expf(-logf(10000.f) * (float)a / (float)(TEMBD / 2 - 1));
        float ang = (float)t[b] * fr;
        temb[b * TEMBD + a] = sinf(ang);
        temb[b * TEMBD + TEMBD / 2 + a] = cosf(ang);
    }
}

// ---------------------------------------------------------------- CSR build
__global__ __launch_bounds__(256) void csr_hist(const int* __restrict__ row, int* __restrict__ deg)
{
    int i = blockIdx.x * 256 + threadIdx.x;
    if (i < NE) atomicAdd(&deg[row[i]], 1);
}

__global__ __launch_bounds__(256) void csr_scan(const int* __restrict__ deg, int* __restrict__ cursor)
{
    __shared__ int s[256];
    int t = threadIdx.x;
    int base = t * 16;
    int loc[16];
    int sum = 0;
    for (int i = 0; i < 16; i++) { loc[i] = sum; sum += deg[base + i]; }
    s[t] = sum; __syncthreads();
    for (int off = 1; off < 256; off <<= 1) {
        int v = (t >= off) ? s[t - off] : 0;
        __syncthreads();
        s[t] += v;
        __syncthreads();
    }
    int excl = (t == 0) ? 0 : s[t - 1];
    for (int i = 0; i < 16; i++) cursor[base + i] = excl + loc[i];
}

__global__ __launch_bounds__(256) void csr_scatter(
    const int* __restrict__ row, const int* __restrict__ col,
    int* __restrict__ cursor, int* __restrict__ prow, int* __restrict__ pcol)
{
    int i = blockIdx.x * 256 + threadIdx.x;
    if (i < NE) {
        int r = row[i];
        int p = atomicAdd(&cursor[r], 1);
        prow[p] = r;
        pcol[p] = col[i];
    }
}

// ---------------------------------------------------------------- weight convert + k-tile
// layout per weight: [kt][n(N)][kk(32)] bf16
#define WOFF_EMB 0
#define WOFF_L(l) (24576 + (l) * 458752)
#define WOFF_AB 0
#define WOFF_E2 131072
#define WOFF_C1 196608
#define WOFF_N1 262144
#define WOFF_N2 393216
#define W_TOTAL (24576 + 4 * 458752)

__global__ __launch_bounds__(256) void convert_weights(
    const float* __restrict__ W_emb, const float* __restrict__ eW1,
    const float* __restrict__ eW2, const float* __restrict__ cW1,
    const float* __restrict__ nW1, const float* __restrict__ nW2,
    short* __restrict__ wb)
{
    int idx = blockIdx.x * 256 + threadIdx.x;
    if (idx >= W_TOTAL) return;
    if (idx < 24576) {
        int k = idx >> 8, n = idx & 255;
        wb[WOFF_EMB + ((k >> 5) << 13) + (n << 5) + (k & 31)] = f2bf(W_emb[idx]);
        return;
    }
    int r = idx - 24576;
    int l = r / 458752;
    int o = r - l * 458752;
    if (o < 131072) {
        // fused P1|P2 weight: N=512. W'[k][n] = n<256 ? eW1[k][n] : eW1[256+k][n-256]
        int k = o >> 9, n = o & 511;
        const float* src = eW1 + (size_t)l * 513 * 256 +
            (n < 256 ? (size_t)k * 256 + n : (size_t)(256 + k) * 256 + (n - 256));
        wb[WOFF_L(l) + WOFF_AB + ((k >> 5) * 16384) + (n << 5) + (k & 31)] = f2bf(*src);
        return;
    }
    const float* src; int dst; int o2;
    if (o < 196608)      { o2 = o - 131072; src = eW2 + (size_t)l * 65536 + o2;  dst = WOFF_L(l) + WOFF_E2; }
    else if (o < 262144) { o2 = o - 196608; src = cW1 + (size_t)l * 65536 + o2;  dst = WOFF_L(l) + WOFF_C1; }
    else if (o < 393216) { o2 = o - 262144; src = nW1 + (size_t)l * 131072 + o2; dst = WOFF_L(l) + WOFF_N1; }
    else                 { o2 = o - 393216; src = nW2 + (size_t)l * 65536 + o2;  dst = WOFF_L(l) + WOFF_N2; }
    int k = o2 >> 8, n = o2 & 255;
    wb[dst + ((k >> 5) << 13) + (n << 5) + (k & 31)] = f2bf(*src);
}

// ---------------------------------------------------------------- h_in = [h | temb] (bf16)
__global__ __launch_bounds__(256) void build_hin(
    const float* __restrict__ h, const float* __restrict__ temb, short* __restrict__ hin)
{
    int idx = blockIdx.x * 256 + threadIdx.x;   // < 4096*96
    int n = idx / 96;
    int k = idx - n * 96;
    float v = (k < FEATD) ? h[n * FEATD + k] : temb[(n >> 8) * TEMBD + (k - FEATD)];
    hin[idx] = f2bf(v);
}

// ---------------------------------------------------------------- global-direct MFMA GEMM
// out[row, c] = act(A[row,:K] @ W + bias) (+res). No LDS, no barriers.
// A: if A2f!=null, k<256 from A1 (stride 256), k>=256 from fp32 A2f (stride 256).
// W k-tiled [kt][n(Nt)][kk(32)]. grid = (M/16, Nt/256). out/res stride = Nt.
__global__ __launch_bounds__(256) void gemm_direct(
    const short* __restrict__ A1, const float* __restrict__ A2f,
    const short* __restrict__ Wt, const float* __restrict__ bias,
    const short* __restrict__ res, short* __restrict__ out,
    int K, int Nt, int act)
{
    int tid = threadIdx.x;
    int wv = tid >> 6, l = tid & 63;
    int lr = l & 15, q = l >> 4;
    int r0 = blockIdx.x * 16;
    int c0 = blockIdx.y * 256 + wv * 64;
    int ksteps = K >> 5;

    f32x4 acc[4];
    #pragma unroll
    for (int i = 0; i < 4; i++) acc[i] = (f32x4){0.f, 0.f, 0.f, 0.f};

    #pragma unroll 2
    for (int kt = 0; kt < ksteps; kt++) {
        int kk = kt * 32 + q * 8;
        short8 fa;
        if (A2f && kk >= 256) {
            const float* src = &A2f[(size_t)(r0 + lr) * 256 + kk - 256];
            #pragma unroll
            for (int k2 = 0; k2 < 8; k2++) fa[k2] = f2bf(src[k2]);
        } else {
            int strideA = A2f ? 256 : K;
            fa = *(const short8*)&A1[(size_t)(r0 + lr) * strideA + kk];
        }
        short8 fb[4];
        #pragma unroll
        for (int nt = 0; nt < 4; nt++)
            fb[nt] = *(const short8*)&Wt[(size_t)kt * Nt * 32 + (c0 + nt * 16 + lr) * 32 + q * 8];
        #pragma unroll
        for (int nt = 0; nt < 4; nt++)
            acc[nt] = __builtin_amdgcn_mfma_f32_16x16x32_bf16(fa, fb[nt], acc[nt], 0, 0, 0);
    }

    #pragma unroll
    for (int nt = 0; nt < 4; nt++) {
        int col = c0 + nt * 16 + lr;
        float bv = bias ? bias[col] : 0.f;
        #pragma unroll
        for (int rg = 0; rg < 4; rg++) {
            int rrow = r0 + q * 4 + rg;
            float v = acc[nt][rg] + bv;
            if (act) v = silu_f(v);
            size_t oi = (size_t)rrow * Nt + col;
            if (res) v += bf2f(res[oi]);
            out[oi] = f2bf(v);
        }
    }
}

// ---------------------------------------------------------------- fused edge kernel
// 64 CSR-sorted edges/block; weights direct from global (no staging barriers).
__global__ __launch_bounds__(256) void egnn_edge_mfma(
    const short* __restrict__ P12, const float* __restrict__ x,
    const int* __restrict__ prow, const int* __restrict__ pcol,
    const float* __restrict__ w512, const float* __restrict__ eb1,
    const short* __restrict__ wtE2, const float* __restrict__ eb2,
    const short* __restrict__ wtC1, const float* __restrict__ cb1,
    const float* __restrict__ cW2,
    float* __restrict__ m_i, float* __restrict__ x_agg)
{
    __shared__ short m_lds[64 * 296];       // 37888 B
    __shared__ float cd_s[64][3];
    __shared__ float radial_s[64];
    __shared__ int prow_s[64];
    __shared__ int pcol_s[64];
    __shared__ float part[8][256];          // stage-A partials
    __shared__ int rowtag[8];
    __shared__ float wred[4][64];

    int tid = threadIdx.x;
    int e0 = blockIdx.x * 64;
    int wv = tid >> 6, l = tid & 63;
    int lr = l & 15, q = l >> 4;

    if (tid < 64) {
        int r = prow[e0 + tid], c = pcol[e0 + tid];
        prow_s[tid] = r; pcol_s[tid] = c;
        float dx = x[r * 3 + 0] - x[c * 3 + 0];
        float dy = x[r * 3 + 1] - x[c * 3 + 1];
        float dz = x[r * 3 + 2] - x[c * 3 + 2];
        cd_s[tid][0] = dx; cd_s[tid][1] = dy; cd_s[tid][2] = dz;
        radial_s[tid] = dx * dx + dy * dy + dz * dz;
    }
    __syncthreads();

    // ---- phase 1: m = silu(P1[r] + P2[c] + radial*w512 + eb1), vectorized
    {
        int e = tid >> 2, cq = tid & 3;
        int r = prow_s[e], c = pcol_s[e];
        float rad = radial_s[e];
        const short* p1r = P12 + (size_t)r * 512 + cq * 64;
        const short* p2r = P12 + (size_t)c * 512 + 256 + cq * 64;
        #pragma unroll
        for (int j = 0; j < 8; j++) {
            short8 a = *(const short8*)&p1r[j * 8];
            short8 b = *(const short8*)&p2r[j * 8];
            float4 w0 = *(const float4*)&w512[cq * 64 + j * 8];
            float4 w1 = *(const float4*)&w512[cq * 64 + j * 8 + 4];
            float4 b0 = *(const float4*)&eb1[cq * 64 + j * 8];
            float4 b1 = *(const float4*)&eb1[cq * 64 + j * 8 + 4];
            float wv8[8] = {w0.x, w0.y, w0.z, w0.w, w1.x, w1.y, w1.z, w1.w};
            float bb8[8] = {b0.x, b0.y, b0.z, b0.w, b1.x, b1.y, b1.z, b1.w};
            short8 o;
            #pragma unroll
            for (int k2 = 0; k2 < 8; k2++) {
                float v = bf2f(a[k2]) + bf2f(b[k2]) + rad * wv8[k2] + bb8[k2];
                o[k2] = f2bf(silu_f(v));
            }
            *(short8*)&m_lds[mofs(e, cq * 64 + j * 8)] = o;
        }
    }
    __syncthreads();

    f32x4 acc[4][4];
    // ---- phase 2: m_ij = silu(m @ eW2 + eb2); B direct from global
    #pragma unroll
    for (int i = 0; i < 4; i++)
        #pragma unroll
        for (int j = 0; j < 4; j++) acc[i][j] = (f32x4){0.f, 0.f, 0.f, 0.f};
    #pragma unroll 2
    for (int kt = 0; kt < 8; kt++) {
        short8 fa[4], fb[4];
        #pragma unroll
        for (int mt = 0; mt < 4; mt++)
            fa[mt] = *(const short8*)&m_lds[mofs(mt * 16 + lr, kt * 32 + q * 8)];
        #pragma unroll
        for (int nt = 0; nt < 4; nt++)
            fb[nt] = *(const short8*)&wtE2[kt * 8192 + (wv * 64 + nt * 16 + lr) * 32 + q * 8];
        #pragma unroll
        for (int mt = 0; mt < 4; mt++)
            #pragma unroll
            for (int nt = 0; nt < 4; nt++)
                acc[mt][nt] = __builtin_amdgcn_mfma_f32_16x16x32_bf16(fa[mt], fb[nt], acc[mt][nt], 0, 0, 0);
    }
    __syncthreads();   // all fa reads done before overwrite
    #pragma unroll
    for (int nt = 0; nt < 4; nt++) {
        int ccol = wv * 64 + nt * 16 + lr;
        float b2 = eb2[ccol];
        #pragma unroll
        for (int mt = 0; mt < 4; mt++)
            #pragma unroll
            for (int rg = 0; rg < 4; rg++) {
                int e = mt * 16 + q * 4 + rg;
                m_lds[mofs(e, ccol)] = f2bf(silu_f(acc[mt][nt][rg] + b2));
            }
    }
    __syncthreads();

    // ---- m_i segment-sum, stage A: 8-edge chunks, vector reads
    {
        int c8 = (tid & 31) * 8, eg = tid >> 5;
        float a8[8];
        #pragma unroll
        for (int k2 = 0; k2 < 8; k2++) a8[k2] = 0.f;
        int cur = prow_s[eg * 8];
        for (int j = 0; j < 8; j++) {
            int e = eg * 8 + j;
            int r = prow_s[e];
            if (r != cur) {
                #pragma unroll
                for (int k2 = 0; k2 < 8; k2++) {
                    atomicAdd(&m_i[(size_t)cur * 256 + c8 + k2], a8[k2]);
                    a8[k2] = 0.f;
                }
                cur = r;
            }
            short8 mv = *(const short8*)&m_lds[mofs(e, c8)];
            #pragma unroll
            for (int k2 = 0; k2 < 8; k2++) a8[k2] += bf2f(mv[k2]);
        }
        #pragma unroll
        for (int k2 = 0; k2 < 8; k2++) part[eg][c8 + k2] = a8[k2];
        if ((tid & 31) == 0) rowtag[eg] = cur;
    }
    __syncthreads();
    // stage B: merge the 8 chunk partials per column
    {
        int c = tid;
        float a = part[0][c];
        int cur = rowtag[0];
        #pragma unroll
        for (int g = 1; g < 8; g++) {
            if (rowtag[g] != cur) {
                atomicAdd(&m_i[(size_t)cur * 256 + c], a);
                a = 0.f;
                cur = rowtag[g];
            }
            a += part[g][c];
        }
        atomicAdd(&m_i[(size_t)cur * 256 + c], a);
    }

    // ---- phase 3: t3 = silu(m_ij @ cW1 + cb1); w = t3 . cW2
    #pragma unroll
    for (int i = 0; i < 4; i++)
        #pragma unroll
        for (int j = 0; j < 4; j++) acc[i][j] = (f32x4){0.f, 0.f, 0.f, 0.f};
    #pragma unroll 2
    for (int kt = 0; kt < 8; kt++) {
        short8 fa[4], fb[4];
        #pragma unroll
        for (int mt = 0; mt < 4; mt++)
            fa[mt] = *(const short8*)&m_lds[mofs(mt * 16 + lr, kt * 32 + q * 8)];
        #pragma unroll
        for (int nt = 0; nt < 4; nt++)
            fb[nt] = *(const short8*)&wtC1[kt * 8192 + (wv * 64 + nt * 16 + lr) * 32 + q * 8];
        #pragma unroll
        for (int mt = 0; mt < 4; mt++)
            #pragma unroll
            for (int nt = 0; nt < 4; nt++)
                acc[mt][nt] = __builtin_amdgcn_mfma_f32_16x16x32_bf16(fa[mt], fb[nt], acc[mt][nt], 0, 0, 0);
    }
    // epilogue 3: per-lane w partials, shuffle-reduce over the 16 col-lanes
    {
        float wp[4][4];
        #pragma unroll
        for (int i = 0; i < 4; i++)
            #pragma unroll
            for (int j = 0; j < 4; j++) wp[i][j] = 0.f;
        #pragma unroll
        for (int nt = 0; nt < 4; nt++) {
            int ccol = wv * 64 + nt * 16 + lr;
            float b1 = cb1[ccol];
            float c2 = cW2[ccol];
            #pragma unroll
            for (int mt = 0; mt < 4; mt++)
                #pragma unroll
                for (int rg = 0; rg < 4; rg++)
                    wp[mt][rg] += silu_f(acc[mt][nt][rg] + b1) * c2;
        }
        #pragma unroll
        for (int mt = 0; mt < 4; mt++)
            #pragma unroll
            for (int rg = 0; rg < 4; rg++) {
                float v = wp[mt][rg];
                v += __shfl_xor(v, 1, 64);
                v += __shfl_xor(v, 2, 64);
                v += __shfl_xor(v, 4, 64);
                v += __shfl_xor(v, 8, 64);
                if (lr == 0) wred[wv][mt * 16 + q * 4 + rg] = v;
            }
    }
    __syncthreads();
    if (tid < 64) {
        float w = wred[0][tid] + wred[1][tid] + wred[2][tid] + wred[3][tid];
        int r = prow_s[tid];
        atomicAdd(&x_agg[r * 3 + 0], cd_s[tid][0] * w);
        atomicAdd(&x_agg[r * 3 + 1], cd_s[tid][1] * w);
        atomicAdd(&x_agg[r * 3 + 2], cd_s[tid][2] * w);
    }
}

// ---------------------------------------------------------------- x += x_agg
__global__ __launch_bounds__(256) void xupd(float* __restrict__ x, const float* __restrict__ xa)
{
    int i = blockIdx.x * 256 + threadIdx.x;
    if (i < NNODES * 3) x[i] += xa[i];
}

// ---------------------------------------------------------------- loss
__global__ __launch_bounds__(256) void loss_part(
    const float* __restrict__ xfin, const float* __restrict__ xt,
    const float* __restrict__ nc, float* __restrict__ lpart)
{
    __shared__ float red[256];
    int b = blockIdx.x, a = threadIdx.x;
    int base = (b * NA + a) * 3;
    float px = xfin[base + 0] - xt[base + 0];
    float py = xfin[base + 1] - xt[base + 1];
    float pz = xfin[base + 2] - xt[base + 2];
    float mx = block_sum(px, red, a) * (1.f / NA);
    float my = block_sum(py, red, a) * (1.f / NA);
    float mz = block_sum(pz, red, a) * (1.f / NA);
    px -= mx; py -= my; pz -= mz;
    float dx = px - nc[base + 0], dy = py - nc[base + 1], dz = pz - nc[base + 2];
    float s = block_sum(dx * dx + dy * dy + dz * dz, red, a);
    if (a == 0) lpart[b] = s;
}

__global__ void loss_final(const float* __restrict__ lpart, float* __restrict__ out)
{
    if (threadIdx.x == 0) {
        float s = 0.f;
        for (int i = 0; i < NB; i++) s += lpart[i];
        out[0] = s / (float)(NNODES * 3);
    }
}

// ---------------------------------------------------------------- launch
extern "C" void kernel_launch(void* const* d_in, const int* in_sizes, int n_in,
                              void* d_out, int out_size, void* d_ws, size_t ws_size,
                              hipStream_t stream)
{
    (void)in_sizes; (void)n_in; (void)out_size; (void)ws_size;
    const float* h     = (const float*)d_in[0];
    const float* x0    = (const float*)d_in[1];
    const float* noise = (const float*)d_in[2];
    const int*   t     = (const int*)d_in[3];
    const int*   row   = (const int*)d_in[4];
    const int*   col   = (const int*)d_in[5];
    const float* W_emb = (const float*)d_in[6];
    const float* b_emb = (const float*)d_in[7];
    const float* eW1   = (const float*)d_in[8];
    const float* eb1   = (const float*)d_in[9];
    const float* eW2   = (const float*)d_in[10];
    const float* eb2   = (const float*)d_in[11];
    const float* cW1   = (const float*)d_in[12];
    const float* cb1   = (const float*)d_in[13];
    const float* cW2   = (const float*)d_in[14];
    const float* nW1   = (const float*)d_in[15];
    const float* nb1   = (const float*)d_in[16];
    const float* nW2   = (const float*)d_in[17];
    const float* nb2   = (const float*)d_in[18];

    // ---- workspace layout
    float* f = (float*)d_ws;
    size_t fo = 0;
    float* temb    = f + fo; fo += NB * TEMBD;
    float* noise_c = f + fo; fo += NNODES * 3;
    float* xt      = f + fo; fo += NNODES * 3;
    float* x_cur   = f + fo; fo += NNODES * 3;
    float* x_agg   = f + fo; fo += NNODES * 3;
    float* m_i     = f + fo; fo += (size_t)NNODES * HID;
    float* lpart   = f + fo; fo += NB;

    int* iw = (int*)(f + fo);
    size_t io = 0;
    int* deg    = iw + io; io += NNODES;
    int* cursor = iw + io; io += NNODES;
    int* prow   = iw + io; io += NE;
    int* pcol   = iw + io; io += NE;

    size_t sbase_bytes = ((((char*)(iw + io)) - (char*)d_ws) + 15) & ~(size_t)15;
    short* sb = (short*)((char*)d_ws + sbase_bytes);
    short* wb  = sb;
    size_t so = W_TOTAL;
    short* hin = sb + so; so += (size_t)NNODES * 96;
    short* hh  = sb + so; so += (size_t)NNODES * HID;
    short* hh2 = sb + so; so += (size_t)NNODES * HID;
    short* P12 = sb + so; so += (size_t)NNODES * 512;
    short* t1  = sb + so; so += (size_t)NNODES * HID;

    // ---- prep + CSR + weights
    prep_kernel<<<NB, 256, 0, stream>>>(x0, noise, t, noise_c, xt, temb);
    hipMemsetAsync(deg, 0, NNODES * sizeof(int), stream);
    csr_hist<<<NE / 256, 256, 0, stream>>>(row, deg);
    csr_scan<<<1, 256, 0, stream>>>(deg, cursor);
    csr_scatter<<<NE / 256, 256, 0, stream>>>(row, col, cursor, prow, pcol);
    convert_weights<<<W_TOTAL / 256, 256, 0, stream>>>(W_emb, eW1, eW2, cW1, nW1, nW2, wb);

    build_hin<<<(NNODES * 96) / 256, 256, 0, stream>>>(h, temb, hin);
    gemm_direct<<<dim3(NNODES / 16, 1), 256, 0, stream>>>(
        hin, nullptr, wb + WOFF_EMB, b_emb, nullptr, hh, 96, 256, 0);
    hipMemcpyAsync(x_cur, xt, (size_t)NNODES * 3 * sizeof(float), hipMemcpyDeviceToDevice, stream);

    short* hc = hh;
    short* hn = hh2;
    for (int l = 0; l < NL; l++) {
        const short* wl = wb + WOFF_L(l);
        gemm_direct<<<dim3(NNODES / 16, 2), 256, 0, stream>>>(
            hc, nullptr, wl + WOFF_AB, nullptr, nullptr, P12, 256, 512, 0);
        hipMemsetAsync(m_i, 0, (size_t)NNODES * HID * sizeof(float), stream);
        hipMemsetAsync(x_agg, 0, (size_t)NNODES * 3 * sizeof(float), stream);
        egnn_edge_mfma<<<NE / 64, 256, 0, stream>>>(
            P12, x_cur, prow, pcol,
            eW1 + (size_t)l * 513 * 256 + 512 * 256, eb1 + (size_t)l * HID,
            wl + WOFF_E2, eb2 + (size_t)l * HID,
            wl + WOFF_C1, cb1 + (size_t)l * HID,
            cW2 + (size_t)l * HID,
            m_i, x_agg);
        if (l < NL - 1) {
            gemm_direct<<<dim3(NNODES / 16, 1), 256, 0, stream>>>(
                hc, m_i, wl + WOFF_N1, nb1 + (size_t)l * HID, nullptr, t1, 512, 256, 1);
            gemm_direct<<<dim3(NNODES / 16, 1), 256, 0, stream>>>(
                t1, nullptr, wl + WOFF_N2, nb2 + (size_t)l * HID, hc, hn, 256, 256, 0);
            short* tmp = hc; hc = hn; hn = tmp;
        }
        xupd<<<(NNODES * 3 + 255) / 256, 256, 0, stream>>>(x_cur, x_agg);
    }

    loss_part<<<NB, 256, 0, stream>>>(x_cur, xt, noise_c, lpart);
    loss_final<<<1, 64, 0, stream>>>(lpart, (float*)d_out);
}

// Round 4
// 786.598 us; speedup vs baseline: 6.6345x; 1.2793x over previous
//
#include <hip/hip_runtime.h>

#define NB 16
#define NA 256
#define NNODES 4096
#define FEATD 64
#define HID 256
#define TEMBD 32
#define NUMT 100
#define NE 131072
#define NL 4

typedef __attribute__((ext_vector_type(8))) short short8;
typedef __attribute__((ext_vector_type(4))) short short4_t;
typedef __attribute__((ext_vector_type(4))) float f32x4;

// fast silu: v * rcp(1 + exp2(-log2e * v)); ~5 VALU ops, no NR refinement.
__device__ __forceinline__ float silu_f(float v) {
    float s = __builtin_amdgcn_rcpf(1.f + __builtin_amdgcn_exp2f(-1.44269504f * v));
    return v * s;
}

__device__ __forceinline__ short f2bf(float f) {          // RNE (outputs)
    union { float f; unsigned u; } v; v.f = f;
    unsigned r = (v.u + 0x7fffu + ((v.u >> 16) & 1u)) >> 16;
    return (short)r;
}
__device__ __forceinline__ short f2bf_t(float f) {        // truncate (LDS intermediates)
    union { float f; unsigned u; } v; v.f = f;
    return (short)(v.u >> 16);
}
__device__ __forceinline__ float bf2f(short s) {
    union { float f; unsigned u; } v; v.u = ((unsigned)(unsigned short)s) << 16;
    return v.f;
}

__device__ __forceinline__ float block_sum(float v, float* red, int a) {
    red[a] = v; __syncthreads();
    for (int s = 128; s > 0; s >>= 1) {
        if (a < s) red[a] += red[a + s];
        __syncthreads();
    }
    float r = red[0]; __syncthreads();
    return r;
}

// m_lds: row stride 288 shorts, 72-short sub-rows (36 words == 4 mod 32).
__device__ __forceinline__ int mofs(int e, int c) {
    return e * 288 + (c >> 6) * 72 + (c & 63);
}

// ---------------------------------------------------------------- prep
__global__ __launch_bounds__(256) void prep_kernel(
    const float* __restrict__ x0, const float* __restrict__ noise,
    const int* __restrict__ t,
    float* __restrict__ noise_c, float* __restrict__ xt, float* __restrict__ temb)
{
    __shared__ float red[256];
    __shared__ float sab_s[2];
    int b = blockIdx.x, a = threadIdx.x;
    int base = (b * NA + a) * 3;

    float nx = noise[base + 0], ny = noise[base + 1], nz = noise[base + 2];
    float mnx = block_sum(nx, red, a) * (1.f / NA);
    float mny = block_sum(ny, red, a) * (1.f / NA);
    float mnz = block_sum(nz, red, a) * (1.f / NA);
    nx -= mnx; ny -= mny; nz -= mnz;
    noise_c[base + 0] = nx; noise_c[base + 1] = ny; noise_c[base + 2] = nz;

    if (a == 0) {
        int tt = t[b];
        float p = 1.f;
        for (int i = 0; i < NUMT; i++) {
            float beta = 1e-4f + (0.02f - 1e-4f) * (float)i / (float)(NUMT - 1);
            if (i <= tt) p *= (1.f - beta);
        }
        sab_s[0] = sqrtf(p);
        sab_s[1] = sqrtf(1.f - p);
    }
    __syncthreads();
    float sab = sab_s[0], s1ab = sab_s[1];

    float xx = sab * x0[base + 0] + s1ab * nx;
    float xy = sab * x0[base + 1] + s1ab * ny;
    float xz = sab * x0[base + 2] + s1ab * nz;
    float mx = block_sum(xx, red, a) * (1.f / NA);
    float my = block_sum(xy, red, a) * (1.f / NA);
    float mz = block_sum(xz, red, a) * (1.f / NA);
    xt[base + 0] = xx - mx; xt[base + 1] = xy - my; xt[base + 2] = xz - mz;

    if (a < TEMBD / 2) {
        float fr = expf(-logf(10000.f) * (float)a / (float)(TEMBD / 2 - 1));
        float ang = (float)t[b] * fr;
        temb[b * TEMBD + a] = sinf(ang);
        temb[b * TEMBD + TEMBD / 2 + a] = cosf(ang);
    }
}

// ---------------------------------------------------------------- CSR build
__global__ __launch_bounds__(256) void csr_hist(const int* __restrict__ row, int* __restrict__ deg)
{
    int i = blockIdx.x * 256 + threadIdx.x;
    if (i < NE) atomicAdd(&deg[row[i]], 1);
}

__global__ __launch_bounds__(256) void csr_scan(const int* __restrict__ deg, int* __restrict__ cursor)
{
    __shared__ int s[256];
    int t = threadIdx.x;
    int base = t * 16;
    int loc[16];
    int sum = 0;
    for (int i = 0; i < 16; i++) { loc[i] = sum; sum += deg[base + i]; }
    s[t] = sum; __syncthreads();
    for (int off = 1; off < 256; off <<= 1) {
        int v = (t >= off) ? s[t - off] : 0;
        __syncthreads();
        s[t] += v;
        __syncthreads();
    }
    int excl = (t == 0) ? 0 : s[t - 1];
    for (int i = 0; i < 16; i++) cursor[base + i] = excl + loc[i];
}

__global__ __launch_bounds__(256) void csr_scatter(
    const int* __restrict__ row, const int* __restrict__ col,
    int* __restrict__ cursor, int* __restrict__ prow, int* __restrict__ pcol)
{
    int i = blockIdx.x * 256 + threadIdx.x;
    if (i < NE) {
        int r = row[i];
        int p = atomicAdd(&cursor[r], 1);
        prow[p] = r;
        pcol[p] = col[i];
    }
}

// ---------------------------------------------------------------- weight convert + k-tile
// layout per weight: [kt][n(N)][kk(32)] bf16
#define WOFF_EMB 0
#define WOFF_L(l) (24576 + (l) * 458752)
#define WOFF_AB 0
#define WOFF_E2 131072
#define WOFF_C1 196608
#define WOFF_N1 262144
#define WOFF_N2 393216
#define W_TOTAL (24576 + 4 * 458752)

__global__ __launch_bounds__(256) void convert_weights(
    const float* __restrict__ W_emb, const float* __restrict__ eW1,
    const float* __restrict__ eW2, const float* __restrict__ cW1,
    const float* __restrict__ nW1, const float* __restrict__ nW2,
    short* __restrict__ wb)
{
    int idx = blockIdx.x * 256 + threadIdx.x;
    if (idx >= W_TOTAL) return;
    if (idx < 24576) {
        int k = idx >> 8, n = idx & 255;
        wb[WOFF_EMB + ((k >> 5) << 13) + (n << 5) + (k & 31)] = f2bf(W_emb[idx]);
        return;
    }
    int r = idx - 24576;
    int l = r / 458752;
    int o = r - l * 458752;
    if (o < 131072) {
        // fused P1|P2 weight: N=512. W'[k][n] = n<256 ? eW1[k][n] : eW1[256+k][n-256]
        int k = o >> 9, n = o & 511;
        const float* src = eW1 + (size_t)l * 513 * 256 +
            (n < 256 ? (size_t)k * 256 + n : (size_t)(256 + k) * 256 + (n - 256));
        wb[WOFF_L(l) + WOFF_AB + ((k >> 5) * 16384) + (n << 5) + (k & 31)] = f2bf(*src);
        return;
    }
    const float* src; int dst; int o2;
    if (o < 196608)      { o2 = o - 131072; src = eW2 + (size_t)l * 65536 + o2;  dst = WOFF_L(l) + WOFF_E2; }
    else if (o < 262144) { o2 = o - 196608; src = cW1 + (size_t)l * 65536 + o2;  dst = WOFF_L(l) + WOFF_C1; }
    else if (o < 393216) { o2 = o - 262144; src = nW1 + (size_t)l * 131072 + o2; dst = WOFF_L(l) + WOFF_N1; }
    else                 { o2 = o - 393216; src = nW2 + (size_t)l * 65536 + o2;  dst = WOFF_L(l) + WOFF_N2; }
    int k = o2 >> 8, n = o2 & 255;
    wb[dst + ((k >> 5) << 13) + (n << 5) + (k & 31)] = f2bf(*src);
}

// ---------------------------------------------------------------- h_in = [h | temb] (bf16)
__global__ __launch_bounds__(256) void build_hin(
    const float* __restrict__ h, const float* __restrict__ temb, short* __restrict__ hin)
{
    int idx = blockIdx.x * 256 + threadIdx.x;   // < 4096*96
    int n = idx / 96;
    int k = idx - n * 96;
    float v = (k < FEATD) ? h[n * FEATD + k] : temb[(n >> 8) * TEMBD + (k - FEATD)];
    hin[idx] = f2bf(v);
}

// ---------------------------------------------------------------- global-direct MFMA GEMM
// One wave per block: 16 rows x 64 cols. out = act(A @ W + bias) (+res).
// A: if A2f!=null, k<256 from A1 (stride 256), k>=256 from fp32 A2f.
// W k-tiled [kt][n(Nt)][kk(32)]. grid = (M/16, Nt/64). out/res stride = Nt.
__global__ __launch_bounds__(64) void gemm_direct(
    const short* __restrict__ A1, const float* __restrict__ A2f,
    const short* __restrict__ Wt, const float* __restrict__ bias,
    const short* __restrict__ res, short* __restrict__ out,
    int K, int Nt, int act)
{
    int l = threadIdx.x;
    int lr = l & 15, q = l >> 4;
    int r0 = blockIdx.x * 16;
    int c0 = blockIdx.y * 64;
    int ksteps = K >> 5;

    f32x4 acc[4];
    #pragma unroll
    for (int i = 0; i < 4; i++) acc[i] = (f32x4){0.f, 0.f, 0.f, 0.f};

    #pragma unroll 2
    for (int kt = 0; kt < ksteps; kt++) {
        int kk = kt * 32 + q * 8;
        short8 fa;
        if (A2f && kk >= 256) {
            const float* src = &A2f[(size_t)(r0 + lr) * 256 + kk - 256];
            #pragma unroll
            for (int k2 = 0; k2 < 8; k2++) fa[k2] = f2bf(src[k2]);
        } else {
            int strideA = A2f ? 256 : K;
            fa = *(const short8*)&A1[(size_t)(r0 + lr) * strideA + kk];
        }
        short8 fb[4];
        #pragma unroll
        for (int nt = 0; nt < 4; nt++)
            fb[nt] = *(const short8*)&Wt[(size_t)kt * Nt * 32 + (c0 + nt * 16 + lr) * 32 + q * 8];
        #pragma unroll
        for (int nt = 0; nt < 4; nt++)
            acc[nt] = __builtin_amdgcn_mfma_f32_16x16x32_bf16(fa, fb[nt], acc[nt], 0, 0, 0);
    }

    #pragma unroll
    for (int nt = 0; nt < 4; nt++) {
        int col = c0 + nt * 16 + lr;
        float bv = bias ? bias[col] : 0.f;
        #pragma unroll
        for (int rg = 0; rg < 4; rg++) {
            int rrow = r0 + q * 4 + rg;
            float v = acc[nt][rg] + bv;
            if (act) v = silu_f(v);
            size_t oi = (size_t)rrow * Nt + col;
            if (res) v += bf2f(res[oi]);
            out[oi] = f2bf(v);
        }
    }
}

// ---------------------------------------------------------------- fused edge kernel
// 64 CSR-sorted edges/block; 4 blocks/CU (LDS 39.4KB, VGPR capped 128).
__global__ __launch_bounds__(256, 4) void egnn_edge_mfma(
    const short* __restrict__ P12, const float* __restrict__ x,
    const int* __restrict__ prow, const int* __restrict__ pcol,
    const float* __restrict__ w512, const float* __restrict__ eb1,
    const short* __restrict__ wtE2, const float* __restrict__ eb2,
    const short* __restrict__ wtC1, const float* __restrict__ cb1,
    const float* __restrict__ cW2,
    float* __restrict__ m_i, float* __restrict__ x_agg)
{
    __shared__ short m_lds[64 * 288];       // 36864 B
    __shared__ float cd_s[64][3];
    __shared__ float radial_s[64];
    __shared__ int prow_s[64];
    __shared__ int pcol_s[64];
    __shared__ float wred[4][64];

    int tid = threadIdx.x;
    int e0 = blockIdx.x * 64;
    int wv = tid >> 6, l = tid & 63;
    int lr = l & 15, q = l >> 4;

    if (tid < 64) {
        int r = prow[e0 + tid], c = pcol[e0 + tid];
        prow_s[tid] = r; pcol_s[tid] = c;
        float dx = x[r * 3 + 0] - x[c * 3 + 0];
        float dy = x[r * 3 + 1] - x[c * 3 + 1];
        float dz = x[r * 3 + 2] - x[c * 3 + 2];
        cd_s[tid][0] = dx; cd_s[tid][1] = dy; cd_s[tid][2] = dz;
        radial_s[tid] = dx * dx + dy * dy + dz * dz;
    }
    __syncthreads();

    // ---- phase 1: m = silu(P1[r] + P2[c] + radial*w512 + eb1)
    // lane map: 4 lanes/edge read CONTIGUOUS 64B per instruction (16 lines/instr)
    {
        int e = tid >> 2, cq = tid & 3;
        int r = prow_s[e], c = pcol_s[e];
        float rad = radial_s[e];
        const short* p1r = P12 + (size_t)r * 512;
        const short* p2r = P12 + (size_t)c * 512 + 256;
        #pragma unroll
        for (int j = 0; j < 8; j++) {
            int cb = (j >> 1) * 64 + (j & 1) * 32 + cq * 8;
            short8 a = *(const short8*)&p1r[cb];
            short8 b = *(const short8*)&p2r[cb];
            float4 w0 = *(const float4*)&w512[cb];
            float4 w1 = *(const float4*)&w512[cb + 4];
            float4 b0 = *(const float4*)&eb1[cb];
            float4 b1 = *(const float4*)&eb1[cb + 4];
            float wv8[8] = {w0.x, w0.y, w0.z, w0.w, w1.x, w1.y, w1.z, w1.w};
            float bb8[8] = {b0.x, b0.y, b0.z, b0.w, b1.x, b1.y, b1.z, b1.w};
            short8 o;
            #pragma unroll
            for (int k2 = 0; k2 < 8; k2++) {
                float v = bf2f(a[k2]) + bf2f(b[k2]) + rad * wv8[k2] + bb8[k2];
                o[k2] = f2bf_t(silu_f(v));
            }
            *(short8*)&m_lds[mofs(e, cb)] = o;
        }
    }
    __syncthreads();

    f32x4 acc[4][4];
    // ---- phase 2: m_ij = silu(m @ eW2 + eb2); B direct from global
    #pragma unroll
    for (int i = 0; i < 4; i++)
        #pragma unroll
        for (int j = 0; j < 4; j++) acc[i][j] = (f32x4){0.f, 0.f, 0.f, 0.f};
    #pragma unroll 2
    for (int kt = 0; kt < 8; kt++) {
        short8 fa[4], fb[4];
        #pragma unroll
        for (int mt = 0; mt < 4; mt++)
            fa[mt] = *(const short8*)&m_lds[mofs(mt * 16 + lr, kt * 32 + q * 8)];
        #pragma unroll
        for (int nt = 0; nt < 4; nt++)
            fb[nt] = *(const short8*)&wtE2[kt * 8192 + (wv * 64 + nt * 16 + lr) * 32 + q * 8];
        #pragma unroll
        for (int mt = 0; mt < 4; mt++)
            #pragma unroll
            for (int nt = 0; nt < 4; nt++)
                acc[mt][nt] = __builtin_amdgcn_mfma_f32_16x16x32_bf16(fa[mt], fb[nt], acc[mt][nt], 0, 0, 0);
    }
    __syncthreads();   // all fa reads done before overwrite
    #pragma unroll
    for (int nt = 0; nt < 4; nt++) {
        int ccol = wv * 64 + nt * 16 + lr;
        float b2 = eb2[ccol];
        #pragma unroll
        for (int mt = 0; mt < 4; mt++)
            #pragma unroll
            for (int rg = 0; rg < 4; rg++) {
                int e = mt * 16 + q * 4 + rg;
                m_lds[mofs(e, ccol)] = f2bf_t(silu_f(acc[mt][nt][rg] + b2));
            }
    }
    __syncthreads();

    // ---- phase 3: t3 = silu(m_ij @ cW1 + cb1); w = t3 . cW2
    #pragma unroll
    for (int i = 0; i < 4; i++)
        #pragma unroll
        for (int j = 0; j < 4; j++) acc[i][j] = (f32x4){0.f, 0.f, 0.f, 0.f};
    #pragma unroll 2
    for (int kt = 0; kt < 8; kt++) {
        short8 fa[4], fb[4];
        #pragma unroll
        for (int mt = 0; mt < 4; mt++)
            fa[mt] = *(const short8*)&m_lds[mofs(mt * 16 + lr, kt * 32 + q * 8)];
        #pragma unroll
        for (int nt = 0; nt < 4; nt++)
            fb[nt] = *(const short8*)&wtC1[kt * 8192 + (wv * 64 + nt * 16 + lr) * 32 + q * 8];
        #pragma unroll
        for (int mt = 0; mt < 4; mt++)
            #pragma unroll
            for (int nt = 0; nt < 4; nt++)
                acc[mt][nt] = __builtin_amdgcn_mfma_f32_16x16x32_bf16(fa[mt], fb[nt], acc[mt][nt], 0, 0, 0);
    }

    // ---- m_i segment-sum while phase-3 MFMAs drain:
    // wave wv owns edges [wv*16, wv*16+16); lane owns 4 columns; flush runs.
    {
        int ebase = wv * 16;
        int c4 = l * 4;
        int lofs = (c4 >> 6) * 72 + (c4 & 63);
        float a0 = 0.f, a1 = 0.f, a2 = 0.f, a3 = 0.f;
        int cur = prow_s[ebase];
        #pragma unroll
        for (int j = 0; j < 16; j++) {
            int e = ebase + j;
            int r = prow_s[e];
            if (r != cur) {
                float* dst = &m_i[(size_t)cur * 256 + c4];
                atomicAdd(dst + 0, a0); atomicAdd(dst + 1, a1);
                atomicAdd(dst + 2, a2); atomicAdd(dst + 3, a3);
                a0 = a1 = a2 = a3 = 0.f;
                cur = r;
            }
            short4_t mv = *(const short4_t*)&m_lds[e * 288 + lofs];
            a0 += bf2f(mv[0]); a1 += bf2f(mv[1]);
            a2 += bf2f(mv[2]); a3 += bf2f(mv[3]);
        }
        float* dst = &m_i[(size_t)cur * 256 + c4];
        atomicAdd(dst + 0, a0); atomicAdd(dst + 1, a1);
        atomicAdd(dst + 2, a2); atomicAdd(dst + 3, a3);
    }

    // ---- epilogue 3: per-lane w partials, shuffle-reduce over 16 col-lanes
    {
        float wp[4][4];
        #pragma unroll
        for (int i = 0; i < 4; i++)
            #pragma unroll
            for (int j = 0; j < 4; j++) wp[i][j] = 0.f;
        #pragma unroll
        for (int nt = 0; nt < 4; nt++) {
            int ccol = wv * 64 + nt * 16 + lr;
            float b1 = cb1[ccol];
            float c2 = cW2[ccol];
            #pragma unroll
            for (int mt = 0; mt < 4; mt++)
                #pragma unroll
                for (int rg = 0; rg < 4; rg++)
                    wp[mt][rg] += silu_f(acc[mt][nt][rg] + b1) * c2;
        }
        #pragma unroll
        for (int mt = 0; mt < 4; mt++)
            #pragma unroll
            for (int rg = 0; rg < 4; rg++) {
                float v = wp[mt][rg];
                v += __shfl_xor(v, 1, 64);
                v += __shfl_xor(v, 2, 64);
                v += __shfl_xor(v, 4, 64);
                v += __shfl_xor(v, 8, 64);
                if (lr == 0) wred[wv][mt * 16 + q * 4 + rg] = v;
            }
    }
    __syncthreads();
    if (tid < 64) {
        float w = wred[0][tid] + wred[1][tid] + wred[2][tid] + wred[3][tid];
        int r = prow_s[tid];
        atomicAdd(&x_agg[r * 3 + 0], cd_s[tid][0] * w);
        atomicAdd(&x_agg[r * 3 + 1], cd_s[tid][1] * w);
        atomicAdd(&x_agg[r * 3 + 2], cd_s[tid][2] * w);
    }
}

// ---------------------------------------------------------------- zero m_i + x_agg
__global__ __launch_bounds__(256) void zero_init(float* __restrict__ m_i, float* __restrict__ xa)
{
    int i = blockIdx.x * 256 + threadIdx.x;   // grid covers NNODES*256
    m_i[i] = 0.f;
    if (i < NNODES * 3) xa[i] = 0.f;
}

// ---------------------------------------------------------------- x += xa; xa=0; m_i=0
__global__ __launch_bounds__(256) void xupd_zero(
    float* __restrict__ x, float* __restrict__ xa, float* __restrict__ m_i)
{
    int i = blockIdx.x * 256 + threadIdx.x;
    m_i[i] = 0.f;
    if (i < NNODES * 3) { x[i] += xa[i]; xa[i] = 0.f; }
}

__global__ __launch_bounds__(256) void xupd(float* __restrict__ x, const float* __restrict__ xa)
{
    int i = blockIdx.x * 256 + threadIdx.x;
    if (i < NNODES * 3) x[i] += xa[i];
}

// ---------------------------------------------------------------- loss
__global__ __launch_bounds__(256) void loss_part(
    const float* __restrict__ xfin, const float* __restrict__ xt,
    const float* __restrict__ nc, float* __restrict__ lpart)
{
    __shared__ float red[256];
    int b = blockIdx.x, a = threadIdx.x;
    int base = (b * NA + a) * 3;
    float px = xfin[base + 0] - xt[base + 0];
    float py = xfin[base + 1] - xt[base + 1];
    float pz = xfin[base + 2] - xt[base + 2];
    float mx = block_sum(px, red, a) * (1.f / NA);
    float my = block_sum(py, red, a) * (1.f / NA);
    float mz = block_sum(pz, red, a) * (1.f / NA);
    px -= mx; py -= my; pz -= mz;
    float dx = px - nc[base + 0], dy = py - nc[base + 1], dz = pz - nc[base + 2];
    float s = block_sum(dx * dx + dy * dy + dz * dz, red, a);
    if (a == 0) lpart[b] = s;
}

__global__ void loss_final(const float* __restrict__ lpart, float* __restrict__ out)
{
    if (threadIdx.x == 0) {
        float s = 0.f;
        for (int i = 0; i < NB; i++) s += lpart[i];
        out[0] = s / (float)(NNODES * 3);
    }
}

// ---------------------------------------------------------------- launch
extern "C" void kernel_launch(void* const* d_in, const int* in_sizes, int n_in,
                              void* d_out, int out_size, void* d_ws, size_t ws_size,
                              hipStream_t stream)
{
    (void)in_sizes; (void)n_in; (void)out_size; (void)ws_size;
    const float* h     = (const float*)d_in[0];
    const float* x0    = (const float*)d_in[1];
    const float* noise = (const float*)d_in[2];
    const int*   t     = (const int*)d_in[3];
    const int*   row   = (const int*)d_in[4];
    const int*   col   = (const int*)d_in[5];
    const float* W_emb = (const float*)d_in[6];
    const float* b_emb = (const float*)d_in[7];
    const float* eW1   = (const float*)d_in[8];
    const float* eb1   = (const float*)d_in[9];
    const float* eW2   = (const float*)d_in[10];
    const float* eb2   = (const float*)d_in[11];
    const float* cW1   = (const float*)d_in[12];
    const float* cb1   = (const float*)d_in[13];
    const float* cW2   = (const float*)d_in[14];
    const float* nW1   = (const float*)d_in[15];
    const float* nb1   = (const float*)d_in[16];
    const float* nW2   = (const float*)d_in[17];
    const float* nb2   = (const float*)d_in[18];

    // ---- workspace layout
    float* f = (float*)d_ws;
    size_t fo = 0;
    float* temb    = f + fo; fo += NB * TEMBD;
    float* noise_c = f + fo; fo += NNODES * 3;
    float* xt      = f + fo; fo += NNODES * 3;
    float* x_cur   = f + fo; fo += NNODES * 3;
    float* x_agg   = f + fo; fo += NNODES * 3;
    float* m_i     = f + fo; fo += (size_t)NNODES * HID;
    float* lpart   = f + fo; fo += NB;

    int* iw = (int*)(f + fo);
    size_t io = 0;
    int* deg    = iw + io; io += NNODES;
    int* cursor = iw + io; io += NNODES;
    int* prow   = iw + io; io += NE;
    int* pcol   = iw + io; io += NE;

    size_t sbase_bytes = ((((char*)(iw + io)) - (char*)d_ws) + 15) & ~(size_t)15;
    short* sb = (short*)((char*)d_ws + sbase_bytes);
    short* wb  = sb;
    size_t so = W_TOTAL;
    short* hin = sb + so; so += (size_t)NNODES * 96;
    short* hh  = sb + so; so += (size_t)NNODES * HID;
    short* hh2 = sb + so; so += (size_t)NNODES * HID;
    short* P12 = sb + so; so += (size_t)NNODES * 512;
    short* t1  = sb + so; so += (size_t)NNODES * HID;

    // ---- prologue: prep, CSR, weights, embedding
    prep_kernel<<<NB, 256, 0, stream>>>(x0, noise, t, noise_c, xt, temb);
    hipMemsetAsync(deg, 0, NNODES * sizeof(int), stream);
    csr_hist<<<NE / 256, 256, 0, stream>>>(row, deg);
    csr_scan<<<1, 256, 0, stream>>>(deg, cursor);
    csr_scatter<<<NE / 256, 256, 0, stream>>>(row, col, cursor, prow, pcol);
    convert_weights<<<W_TOTAL / 256, 256, 0, stream>>>(W_emb, eW1, eW2, cW1, nW1, nW2, wb);
    zero_init<<<NNODES, 256, 0, stream>>>(m_i, x_agg);

    build_hin<<<(NNODES * 96) / 256, 256, 0, stream>>>(h, temb, hin);
    gemm_direct<<<dim3(NNODES / 16, 4), 64, 0, stream>>>(
        hin, nullptr, wb + WOFF_EMB, b_emb, nullptr, hh, 96, 256, 0);
    hipMemcpyAsync(x_cur, xt, (size_t)NNODES * 3 * sizeof(float), hipMemcpyDeviceToDevice, stream);

    short* hc = hh;
    short* hn = hh2;
    for (int l = 0; l < NL; l++) {
        const short* wl = wb + WOFF_L(l);
        gemm_direct<<<dim3(NNODES / 16, 8), 64, 0, stream>>>(
            hc, nullptr, wl + WOFF_AB, nullptr, nullptr, P12, 256, 512, 0);
        egnn_edge_mfma<<<NE / 64, 256, 0, stream>>>(
            P12, x_cur, prow, pcol,
            eW1 + (size_t)l * 513 * 256 + 512 * 256, eb1 + (size_t)l * HID,
            wl + WOFF_E2, eb2 + (size_t)l * HID,
            wl + WOFF_C1, cb1 + (size_t)l * HID,
            cW2 + (size_t)l * HID,
            m_i, x_agg);
        if (l < NL - 1) {
            gemm_direct<<<dim3(NNODES / 16, 4), 64, 0, stream>>>(
                hc, m_i, wl + WOFF_N1, nb1 + (size_t)l * HID, nullptr, t1, 512, 256, 1);
            gemm_direct<<<dim3(NNODES / 16, 4), 64, 0, stream>>>(
                t1, nullptr, wl + WOFF_N2, nb2 + (size_t)l * HID, hc, hn, 256, 256, 0);
            xupd_zero<<<NNODES, 256, 0, stream>>>(x_cur, x_agg, m_i);
            short* tmp = hc; hc = hn; hn = tmp;
        } else {
            xupd<<<(NNODES * 3 + 255) / 256, 256, 0, stream>>>(x_cur, x_agg);
        }
    }

    loss_part<<<NB, 256, 0, stream>>>(x_cur, xt, noise_c, lpart);
    loss_final<<<1, 64, 0, stream>>>(lpart, (float*)d_out);
}

// Round 5
// 578.728 us; speedup vs baseline: 9.0175x; 1.3592x over previous
//
#include <hip/hip_runtime.h>

#define NB 16
#define NA 256
#define NNODES 4096
#define FEATD 64
#define HID 256
#define TEMBD 32
#define NUMT 100
#define NE 131072
#define NL 4
#define NCHUNK (NE / 16)   // 8192 16-edge chunks

typedef __attribute__((ext_vector_type(8))) short short8;
typedef __attribute__((ext_vector_type(4))) short short4_t;
typedef __attribute__((ext_vector_type(4))) float f32x4;

// fast silu: v * rcp(1 + exp2(-log2e * v))
__device__ __forceinline__ float silu_f(float v) {
    float s = __builtin_amdgcn_rcpf(1.f + __builtin_amdgcn_exp2f(-1.44269504f * v));
    return v * s;
}

__device__ __forceinline__ short f2bf(float f) {          // RNE
    union { float f; unsigned u; } v; v.f = f;
    unsigned r = (v.u + 0x7fffu + ((v.u >> 16) & 1u)) >> 16;
    return (short)r;
}
__device__ __forceinline__ short f2bf_t(float f) {        // truncate (intermediates)
    union { float f; unsigned u; } v; v.f = f;
    return (short)(v.u >> 16);
}
__device__ __forceinline__ float bf2f(short s) {
    union { float f; unsigned u; } v; v.u = ((unsigned)(unsigned short)s) << 16;
    return v.f;
}

__device__ __forceinline__ float block_sum(float v, float* red, int a) {
    red[a] = v; __syncthreads();
    for (int s = 128; s > 0; s >>= 1) {
        if (a < s) red[a] += red[a + s];
        __syncthreads();
    }
    float r = red[0]; __syncthreads();
    return r;
}

// m_lds: row stride 288 shorts, 72-short sub-rows.
__device__ __forceinline__ int mofs(int e, int c) {
    return e * 288 + (c >> 6) * 72 + (c & 63);
}

// ---------------------------------------------------------------- prep
__global__ __launch_bounds__(256) void prep_kernel(
    const float* __restrict__ x0, const float* __restrict__ noise,
    const int* __restrict__ t,
    float* __restrict__ noise_c, float* __restrict__ xt, float* __restrict__ temb)
{
    __shared__ float red[256];
    __shared__ float sab_s[2];
    int b = blockIdx.x, a = threadIdx.x;
    int base = (b * NA + a) * 3;

    float nx = noise[base + 0], ny = noise[base + 1], nz = noise[base + 2];
    float mnx = block_sum(nx, red, a) * (1.f / NA);
    float mny = block_sum(ny, red, a) * (1.f / NA);
    float mnz = block_sum(nz, red, a) * (1.f / NA);
    nx -= mnx; ny -= mny; nz -= mnz;
    noise_c[base + 0] = nx; noise_c[base + 1] = ny; noise_c[base + 2] = nz;

    if (a == 0) {
        int tt = t[b];
        float p = 1.f;
        for (int i = 0; i < NUMT; i++) {
            float beta = 1e-4f + (0.02f - 1e-4f) * (float)i / (float)(NUMT - 1);
            if (i <= tt) p *= (1.f - beta);
        }
        sab_s[0] = sqrtf(p);
        sab_s[1] = sqrtf(1.f - p);
    }
    __syncthreads();
    float sab = sab_s[0], s1ab = sab_s[1];

    float xx = sab * x0[base + 0] + s1ab * nx;
    float xy = sab * x0[base + 1] + s1ab * ny;
    float xz = sab * x0[base + 2] + s1ab * nz;
    float mx = block_sum(xx, red, a) * (1.f / NA);
    float my = block_sum(xy, red, a) * (1.f / NA);
    float mz = block_sum(xz, red, a) * (1.f / NA);
    xt[base + 0] = xx - mx; xt[base + 1] = xy - my; xt[base + 2] = xz - mz;

    if (a < TEMBD / 2) {
        float fr = expf(-logf(10000.f) * (float)a / (float)(TEMBD / 2 - 1));
        float ang = (float)t[b] * fr;
        temb[b * TEMBD + a] = sinf(ang);
        temb[b * TEMBD + TEMBD / 2 + a] = cosf(ang);
    }
}

// ---------------------------------------------------------------- CSR build
__global__ __launch_bounds__(256) void csr_hist(const int* __restrict__ row, int* __restrict__ deg)
{
    int i = blockIdx.x * 256 + threadIdx.x;
    if (i < NE) atomicAdd(&deg[row[i]], 1);
}

__global__ __launch_bounds__(256) void csr_scan(const int* __restrict__ deg, int* __restrict__ cursor)
{
    __shared__ int s[256];
    int t = threadIdx.x;
    int base = t * 16;
    int loc[16];
    int sum = 0;
    for (int i = 0; i < 16; i++) { loc[i] = sum; sum += deg[base + i]; }
    s[t] = sum; __syncthreads();
    for (int off = 1; off < 256; off <<= 1) {
        int v = (t >= off) ? s[t - off] : 0;
        __syncthreads();
        s[t] += v;
        __syncthreads();
    }
    int excl = (t == 0) ? 0 : s[t - 1];
    for (int i = 0; i < 16; i++) cursor[base + i] = excl + loc[i];
}

__global__ __launch_bounds__(256) void csr_scatter(
    const int* __restrict__ row, const int* __restrict__ col,
    int* __restrict__ cursor, int* __restrict__ prow, int* __restrict__ pcol)
{
    int i = blockIdx.x * 256 + threadIdx.x;
    if (i < NE) {
        int r = row[i];
        int p = atomicAdd(&cursor[r], 1);
        prow[p] = r;
        pcol[p] = col[i];
    }
}

// ---------------------------------------------------------------- weight convert + k-tile
// layout per weight: [kt][n(N)][kk(32)] bf16
#define WOFF_EMB 0
#define WOFF_L(l) (24576 + (l) * 458752)
#define WOFF_AB 0
#define WOFF_E2 131072
#define WOFF_C1 196608
#define WOFF_N1 262144
#define WOFF_N2 393216
#define W_TOTAL (24576 + 4 * 458752)

__global__ __launch_bounds__(256) void convert_weights(
    const float* __restrict__ W_emb, const float* __restrict__ eW1,
    const float* __restrict__ eW2, const float* __restrict__ cW1,
    const float* __restrict__ nW1, const float* __restrict__ nW2,
    short* __restrict__ wb)
{
    int idx = blockIdx.x * 256 + threadIdx.x;
    if (idx >= W_TOTAL) return;
    if (idx < 24576) {
        int k = idx >> 8, n = idx & 255;
        wb[WOFF_EMB + ((k >> 5) << 13) + (n << 5) + (k & 31)] = f2bf(W_emb[idx]);
        return;
    }
    int r = idx - 24576;
    int l = r / 458752;
    int o = r - l * 458752;
    if (o < 131072) {
        int k = o >> 9, n = o & 511;
        const float* src = eW1 + (size_t)l * 513 * 256 +
            (n < 256 ? (size_t)k * 256 + n : (size_t)(256 + k) * 256 + (n - 256));
        wb[WOFF_L(l) + WOFF_AB + ((k >> 5) * 16384) + (n << 5) + (k & 31)] = f2bf(*src);
        return;
    }
    const float* src; int dst; int o2;
    if (o < 196608)      { o2 = o - 131072; src = eW2 + (size_t)l * 65536 + o2;  dst = WOFF_L(l) + WOFF_E2; }
    else if (o < 262144) { o2 = o - 196608; src = cW1 + (size_t)l * 65536 + o2;  dst = WOFF_L(l) + WOFF_C1; }
    else if (o < 393216) { o2 = o - 262144; src = nW1 + (size_t)l * 131072 + o2; dst = WOFF_L(l) + WOFF_N1; }
    else                 { o2 = o - 393216; src = nW2 + (size_t)l * 65536 + o2;  dst = WOFF_L(l) + WOFF_N2; }
    int k = o2 >> 8, n = o2 & 255;
    wb[dst + ((k >> 5) << 13) + (n << 5) + (k & 31)] = f2bf(*src);
}

// ---------------------------------------------------------------- h_in = [h | temb] (bf16)
__global__ __launch_bounds__(256) void build_hin(
    const float* __restrict__ h, const float* __restrict__ temb, short* __restrict__ hin)
{
    int idx = blockIdx.x * 256 + threadIdx.x;   // < 4096*96
    int n = idx / 96;
    int k = idx - n * 96;
    float v = (k < FEATD) ? h[n * FEATD + k] : temb[(n >> 8) * TEMBD + (k - FEATD)];
    hin[idx] = f2bf(v);
}

// ---------------------------------------------------------------- emb GEMM + layer0 P12 fused
// 16 nodes/block: hh = hin@W_emb+b (K=96) -> LDS+global ; P12 = hh@AB (K=256,N=512)
__global__ __launch_bounds__(256) void emb_p12_fused(
    const short* __restrict__ hin, const short* __restrict__ wtEmb,
    const float* __restrict__ b_emb, const short* __restrict__ wtAB,
    short* __restrict__ hh, short* __restrict__ P12)
{
    __shared__ short h2s[16 * 264];
    int tid = threadIdx.x;
    int wv = tid >> 6, l = tid & 63;
    int lr = l & 15, q = l >> 4;
    int r0 = blockIdx.x * 16;

    f32x4 acc[4];
    #pragma unroll
    for (int i = 0; i < 4; i++) acc[i] = (f32x4){0.f, 0.f, 0.f, 0.f};
    #pragma unroll
    for (int kt = 0; kt < 3; kt++) {
        int kk = kt * 32 + q * 8;
        short8 fa = *(const short8*)&hin[(size_t)(r0 + lr) * 96 + kk];
        short8 fb[4];
        #pragma unroll
        for (int nt = 0; nt < 4; nt++)
            fb[nt] = *(const short8*)&wtEmb[kt * 8192 + (wv * 64 + nt * 16 + lr) * 32 + q * 8];
        #pragma unroll
        for (int nt = 0; nt < 4; nt++)
            acc[nt] = __builtin_amdgcn_mfma_f32_16x16x32_bf16(fa, fb[nt], acc[nt], 0, 0, 0);
    }
    #pragma unroll
    for (int nt = 0; nt < 4; nt++) {
        int col = wv * 64 + nt * 16 + lr;
        float bv = b_emb[col];
        #pragma unroll
        for (int rg = 0; rg < 4; rg++) {
            int rrow = q * 4 + rg;
            short b = f2bf(acc[nt][rg] + bv);
            hh[(size_t)(r0 + rrow) * 256 + col] = b;
            h2s[rrow * 264 + col] = b;
        }
    }
    __syncthreads();

    f32x4 acc3[8];
    #pragma unroll
    for (int i = 0; i < 8; i++) acc3[i] = (f32x4){0.f, 0.f, 0.f, 0.f};
    #pragma unroll 2
    for (int kt = 0; kt < 8; kt++) {
        short8 fa = *(const short8*)&h2s[lr * 264 + kt * 32 + q * 8];
        #pragma unroll
        for (int nt = 0; nt < 8; nt++) {
            short8 fb = *(const short8*)&wtAB[kt * 16384 + (wv * 128 + nt * 16 + lr) * 32 + q * 8];
            acc3[nt] = __builtin_amdgcn_mfma_f32_16x16x32_bf16(fa, fb, acc3[nt], 0, 0, 0);
        }
    }
    #pragma unroll
    for (int nt = 0; nt < 8; nt++) {
        int col = wv * 128 + nt * 16 + lr;
        #pragma unroll
        for (int rg = 0; rg < 4; rg++)
            P12[(size_t)(r0 + q * 4 + rg) * 512 + col] = f2bf(acc3[nt][rg]);
    }
}

// ---------------------------------------------------------------- fused node MLP + next P12
// t1 = silu([hc|m_i]@nW1+nb1); h' = hc + t1@nW2+nb2 -> hn + LDS; P12 = h'@AB
__global__ __launch_bounds__(256) void node_p12_fused(
    const short* __restrict__ hc, const float* __restrict__ m_i,
    const short* __restrict__ wtN1, const float* __restrict__ nb1,
    const short* __restrict__ wtN2, const float* __restrict__ nb2,
    const short* __restrict__ wtAB,
    short* __restrict__ hn, short* __restrict__ P12)
{
    __shared__ short t1s[16 * 264];
    __shared__ short h2s[16 * 264];
    int tid = threadIdx.x;
    int wv = tid >> 6, l = tid & 63;
    int lr = l & 15, q = l >> 4;
    int r0 = blockIdx.x * 16;

    // stage 1: t1 (K=512)
    f32x4 acc[4];
    #pragma unroll
    for (int i = 0; i < 4; i++) acc[i] = (f32x4){0.f, 0.f, 0.f, 0.f};
    #pragma unroll 2
    for (int kt = 0; kt < 16; kt++) {
        int kk = kt * 32 + q * 8;
        short8 fa;
        if (kk < 256) {
            fa = *(const short8*)&hc[(size_t)(r0 + lr) * 256 + kk];
        } else {
            const float* src = &m_i[(size_t)(r0 + lr) * 256 + kk - 256];
            #pragma unroll
            for (int k2 = 0; k2 < 8; k2++) fa[k2] = f2bf(src[k2]);
        }
        short8 fb[4];
        #pragma unroll
        for (int nt = 0; nt < 4; nt++)
            fb[nt] = *(const short8*)&wtN1[kt * 8192 + (wv * 64 + nt * 16 + lr) * 32 + q * 8];
        #pragma unroll
        for (int nt = 0; nt < 4; nt++)
            acc[nt] = __builtin_amdgcn_mfma_f32_16x16x32_bf16(fa, fb[nt], acc[nt], 0, 0, 0);
    }
    #pragma unroll
    for (int nt = 0; nt < 4; nt++) {
        int col = wv * 64 + nt * 16 + lr;
        float bv = nb1[col];
        #pragma unroll
        for (int rg = 0; rg < 4; rg++)
            t1s[(q * 4 + rg) * 264 + col] = f2bf_t(silu_f(acc[nt][rg] + bv));
    }
    __syncthreads();

    // stage 2: h' = hc + t1@nW2 + nb2
    f32x4 acc2[4];
    #pragma unroll
    for (int i = 0; i < 4; i++) acc2[i] = (f32x4){0.f, 0.f, 0.f, 0.f};
    #pragma unroll 2
    for (int kt = 0; kt < 8; kt++) {
        short8 fa = *(const short8*)&t1s[lr * 264 + kt * 32 + q * 8];
        short8 fb[4];
        #pragma unroll
        for (int nt = 0; nt < 4; nt++)
            fb[nt] = *(const short8*)&wtN2[kt * 8192 + (wv * 64 + nt * 16 + lr) * 32 + q * 8];
        #pragma unroll
        for (int nt = 0; nt < 4; nt++)
            acc2[nt] = __builtin_amdgcn_mfma_f32_16x16x32_bf16(fa, fb[nt], acc2[nt], 0, 0, 0);
    }
    #pragma unroll
    for (int nt = 0; nt < 4; nt++) {
        int col = wv * 64 + nt * 16 + lr;
        float bv = nb2[col];
        #pragma unroll
        for (int rg = 0; rg < 4; rg++) {
            int rrow = q * 4 + rg;
            float v = acc2[nt][rg] + bv + bf2f(hc[(size_t)(r0 + rrow) * 256 + col]);
            short b = f2bf(v);
            hn[(size_t)(r0 + rrow) * 256 + col] = b;
            h2s[rrow * 264 + col] = b;
        }
    }
    __syncthreads();

    // stage 3: P12 = h' @ AB (N=512)
    f32x4 acc3[8];
    #pragma unroll
    for (int i = 0; i < 8; i++) acc3[i] = (f32x4){0.f, 0.f, 0.f, 0.f};
    #pragma unroll 2
    for (int kt = 0; kt < 8; kt++) {
        short8 fa = *(const short8*)&h2s[lr * 264 + kt * 32 + q * 8];
        #pragma unroll
        for (int nt = 0; nt < 8; nt++) {
            short8 fb = *(const short8*)&wtAB[kt * 16384 + (wv * 128 + nt * 16 + lr) * 32 + q * 8];
            acc3[nt] = __builtin_amdgcn_mfma_f32_16x16x32_bf16(fa, fb, acc3[nt], 0, 0, 0);
        }
    }
    #pragma unroll
    for (int nt = 0; nt < 8; nt++) {
        int col = wv * 128 + nt * 16 + lr;
        #pragma unroll
        for (int rg = 0; rg < 4; rg++)
            P12[(size_t)(r0 + q * 4 + rg) * 512 + col] = f2bf(acc3[nt][rg]);
    }
}

// ---------------------------------------------------------------- fused edge kernel
// 64 CSR-sorted edges/block, 4 chunks of 16. NO global atomics: boundary runs
// go to per-chunk slots, interior runs are exclusive -> plain stores.
__global__ __launch_bounds__(256, 4) void egnn_edge_mfma(
    const short* __restrict__ P12, const float* __restrict__ x,
    const int* __restrict__ prow, const int* __restrict__ pcol,
    const float* __restrict__ w512, const float* __restrict__ eb1,
    const short* __restrict__ wtE2, const float* __restrict__ eb2,
    const short* __restrict__ wtC1, const float* __restrict__ cb1,
    const float* __restrict__ cW2,
    float* __restrict__ m_i, float* __restrict__ x_agg,
    float* __restrict__ msl0, float* __restrict__ msl1,
    float* __restrict__ xsl0, float* __restrict__ xsl1,
    int* __restrict__ tag0, int* __restrict__ tag1)
{
    __shared__ short m_lds[64 * 288];       // 36864 B
    __shared__ float cd_s[64][3];
    __shared__ float radial_s[64];
    __shared__ int prow_s[64];
    __shared__ float wred[4][64];
    __shared__ float xtmp[64][3];

    int tid = threadIdx.x;
    int e0 = blockIdx.x * 64;
    int wv = tid >> 6, l = tid & 63;
    int lr = l & 15, q = l >> 4;

    if (tid < 64) {
        int r = prow[e0 + tid], c = pcol[e0 + tid];
        prow_s[tid] = r;
        float dx = x[r * 3 + 0] - x[c * 3 + 0];
        float dy = x[r * 3 + 1] - x[c * 3 + 1];
        float dz = x[r * 3 + 2] - x[c * 3 + 2];
        cd_s[tid][0] = dx; cd_s[tid][1] = dy; cd_s[tid][2] = dz;
        radial_s[tid] = dx * dx + dy * dy + dz * dz;
    }
    __syncthreads();

    // ---- phase 1: m = silu(P1[r] + P2[c] + radial*w512 + eb1)
    {
        int e = tid >> 2, cq = tid & 3;
        int r = prow_s[e], c = pcol[e0 + e];
        float rad = radial_s[e];
        const short* p1r = P12 + (size_t)r * 512;
        const short* p2r = P12 + (size_t)c * 512 + 256;
        #pragma unroll
        for (int j = 0; j < 8; j++) {
            int cb = (j >> 1) * 64 + (j & 1) * 32 + cq * 8;
            short8 a = *(const short8*)&p1r[cb];
            short8 b = *(const short8*)&p2r[cb];
            float4 w0 = *(const float4*)&w512[cb];
            float4 w1 = *(const float4*)&w512[cb + 4];
            float4 b0 = *(const float4*)&eb1[cb];
            float4 b1 = *(const float4*)&eb1[cb + 4];
            float wv8[8] = {w0.x, w0.y, w0.z, w0.w, w1.x, w1.y, w1.z, w1.w};
            float bb8[8] = {b0.x, b0.y, b0.z, b0.w, b1.x, b1.y, b1.z, b1.w};
            short8 o;
            #pragma unroll
            for (int k2 = 0; k2 < 8; k2++) {
                float v = bf2f(a[k2]) + bf2f(b[k2]) + rad * wv8[k2] + bb8[k2];
                o[k2] = f2bf_t(silu_f(v));
            }
            *(short8*)&m_lds[mofs(e, cb)] = o;
        }
    }
    __syncthreads();

    f32x4 acc[4][4];
    // ---- phase 2: m_ij = silu(m @ eW2 + eb2)
    #pragma unroll
    for (int i = 0; i < 4; i++)
        #pragma unroll
        for (int j = 0; j < 4; j++) acc[i][j] = (f32x4){0.f, 0.f, 0.f, 0.f};
    #pragma unroll 2
    for (int kt = 0; kt < 8; kt++) {
        short8 fa[4], fb[4];
        #pragma unroll
        for (int mt = 0; mt < 4; mt++)
            fa[mt] = *(const short8*)&m_lds[mofs(mt * 16 + lr, kt * 32 + q * 8)];
        #pragma unroll
        for (int nt = 0; nt < 4; nt++)
            fb[nt] = *(const short8*)&wtE2[kt * 8192 + (wv * 64 + nt * 16 + lr) * 32 + q * 8];
        #pragma unroll
        for (int mt = 0; mt < 4; mt++)
            #pragma unroll
            for (int nt = 0; nt < 4; nt++)
                acc[mt][nt] = __builtin_amdgcn_mfma_f32_16x16x32_bf16(fa[mt], fb[nt], acc[mt][nt], 0, 0, 0);
    }
    __syncthreads();
    #pragma unroll
    for (int nt = 0; nt < 4; nt++) {
        int ccol = wv * 64 + nt * 16 + lr;
        float b2 = eb2[ccol];
        #pragma unroll
        for (int mt = 0; mt < 4; mt++)
            #pragma unroll
            for (int rg = 0; rg < 4; rg++) {
                int e = mt * 16 + q * 4 + rg;
                m_lds[mofs(e, ccol)] = f2bf_t(silu_f(acc[mt][nt][rg] + b2));
            }
    }
    __syncthreads();

    // ---- phase 3: t3 = silu(m_ij @ cW1 + cb1); w = t3 . cW2
    #pragma unroll
    for (int i = 0; i < 4; i++)
        #pragma unroll
        for (int j = 0; j < 4; j++) acc[i][j] = (f32x4){0.f, 0.f, 0.f, 0.f};
    #pragma unroll 2
    for (int kt = 0; kt < 8; kt++) {
        short8 fa[4], fb[4];
        #pragma unroll
        for (int mt = 0; mt < 4; mt++)
            fa[mt] = *(const short8*)&m_lds[mofs(mt * 16 + lr, kt * 32 + q * 8)];
        #pragma unroll
        for (int nt = 0; nt < 4; nt++)
            fb[nt] = *(const short8*)&wtC1[kt * 8192 + (wv * 64 + nt * 16 + lr) * 32 + q * 8];
        #pragma unroll
        for (int mt = 0; mt < 4; mt++)
            #pragma unroll
            for (int nt = 0; nt < 4; nt++)
                acc[mt][nt] = __builtin_amdgcn_mfma_f32_16x16x32_bf16(fa[mt], fb[nt], acc[mt][nt], 0, 0, 0);
    }

    // ---- m_i segment-sum (overlaps phase-3 MFMA drain). Wave wv owns chunk.
    {
        int ebase = wv * 16;
        int c4 = l * 4;
        int lofs = (c4 >> 6) * 72 + (c4 & 63);
        int chunk = blockIdx.x * 4 + wv;
        float a0 = 0.f, a1 = 0.f, a2 = 0.f, a3 = 0.f;
        int cur = prow_s[ebase];
        int nrun = 0;
        #pragma unroll
        for (int j = 0; j < 16; j++) {
            int e = ebase + j;
            int r = prow_s[e];
            if (r != cur) {
                float4 v = {a0, a1, a2, a3};
                if (nrun == 0) *(float4*)&msl0[(size_t)chunk * 256 + c4] = v;
                else           *(float4*)&m_i[(size_t)cur * 256 + c4] = v;  // exclusive
                nrun++; a0 = a1 = a2 = a3 = 0.f; cur = r;
            }
            short4_t mv = *(const short4_t*)&m_lds[e * 288 + lofs];
            a0 += bf2f(mv[0]); a1 += bf2f(mv[1]);
            a2 += bf2f(mv[2]); a3 += bf2f(mv[3]);
        }
        float4 v = {a0, a1, a2, a3};
        if (nrun == 0) *(float4*)&msl0[(size_t)chunk * 256 + c4] = v;
        else           *(float4*)&msl1[(size_t)chunk * 256 + c4] = v;
        if (l == 0) {
            tag0[chunk] = prow_s[ebase];
            tag1[chunk] = nrun ? cur : -1;
        }
    }

    // ---- epilogue 3: per-lane w partials, shuffle-reduce over 16 col-lanes
    {
        float wp[4][4];
        #pragma unroll
        for (int i = 0; i < 4; i++)
            #pragma unroll
            for (int j = 0; j < 4; j++) wp[i][j] = 0.f;
        #pragma unroll
        for (int nt = 0; nt < 4; nt++) {
            int ccol = wv * 64 + nt * 16 + lr;
            float b1 = cb1[ccol];
            float c2 = cW2[ccol];
            #pragma unroll
            for (int mt = 0; mt < 4; mt++)
                #pragma unroll
                for (int rg = 0; rg < 4; rg++)
                    wp[mt][rg] += silu_f(acc[mt][nt][rg] + b1) * c2;
        }
        #pragma unroll
        for (int mt = 0; mt < 4; mt++)
            #pragma unroll
            for (int rg = 0; rg < 4; rg++) {
                float v = wp[mt][rg];
                v += __shfl_xor(v, 1, 64);
                v += __shfl_xor(v, 2, 64);
                v += __shfl_xor(v, 4, 64);
                v += __shfl_xor(v, 8, 64);
                if (lr == 0) wred[wv][mt * 16 + q * 4 + rg] = v;
            }
    }
    __syncthreads();
    if (tid < 64) {
        float w = wred[0][tid] + wred[1][tid] + wred[2][tid] + wred[3][tid];
        xtmp[tid][0] = cd_s[tid][0] * w;
        xtmp[tid][1] = cd_s[tid][1] * w;
        xtmp[tid][2] = cd_s[tid][2] * w;
    }
    __syncthreads();
    if (tid < 64) {
        int e = tid, j = e & 15, wv2 = e >> 4;
        int r = prow_s[e];
        bool leader = (j == 0) || (prow_s[e - 1] != r);
        if (leader) {
            int eend = (wv2 + 1) * 16;
            float sx = 0.f, sy = 0.f, sz = 0.f;
            int k = e;
            while (k < eend && prow_s[k] == r) {
                sx += xtmp[k][0]; sy += xtmp[k][1]; sz += xtmp[k][2]; k++;
            }
            int chunk = blockIdx.x * 4 + wv2;
            if (j == 0)        { xsl0[chunk * 3 + 0] = sx; xsl0[chunk * 3 + 1] = sy; xsl0[chunk * 3 + 2] = sz; }
            else if (k == eend){ xsl1[chunk * 3 + 0] = sx; xsl1[chunk * 3 + 1] = sy; xsl1[chunk * 3 + 2] = sz; }
            else               { x_agg[r * 3 + 0] = sx; x_agg[r * 3 + 1] = sy; x_agg[r * 3 + 2] = sz; }  // exclusive
        }
    }
}

// ---------------------------------------------------------------- slot reduce
// per node: m_i = direct + matching slots ; x_cur += x_direct + matching slots
__global__ __launch_bounds__(256) void reduce_scatter(
    const int* __restrict__ cursor,
    const int* __restrict__ tag0, const int* __restrict__ tag1,
    const float* __restrict__ msl0, const float* __restrict__ msl1,
    const float* __restrict__ xsl0, const float* __restrict__ xsl1,
    float* __restrict__ m_i, const float* __restrict__ x_agg,
    float* __restrict__ x_cur)
{
    int r = blockIdx.x, c = threadIdx.x;
    int end = cursor[r];
    int start = (r == 0) ? 0 : cursor[r - 1];
    float acc = m_i[(size_t)r * 256 + c];
    float xa = (c < 3) ? x_agg[r * 3 + c] : 0.f;
    if (end > start) {
        int cs = start >> 4, ce = (end - 1) >> 4;
        for (int ch = cs; ch <= ce; ch++) {
            if (tag0[ch] == r) {
                acc += msl0[(size_t)ch * 256 + c];
                if (c < 3) xa += xsl0[ch * 3 + c];
            }
            if (tag1[ch] == r) {
                acc += msl1[(size_t)ch * 256 + c];
                if (c < 3) xa += xsl1[ch * 3 + c];
            }
        }
    }
    m_i[(size_t)r * 256 + c] = acc;
    if (c < 3) x_cur[r * 3 + c] += xa;
}

// ---------------------------------------------------------------- loss
__global__ __launch_bounds__(256) void loss_part(
    const float* __restrict__ xfin, const float* __restrict__ xt,
    const float* __restrict__ nc, float* __restrict__ lpart)
{
    __shared__ float red[256];
    int b = blockIdx.x, a = threadIdx.x;
    int base = (b * NA + a) * 3;
    float px = xfin[base + 0] - xt[base + 0];
    float py = xfin[base + 1] - xt[base + 1];
    float pz = xfin[base + 2] - xt[base + 2];
    float mx = block_sum(px, red, a) * (1.f / NA);
    float my = block_sum(py, red, a) * (1.f / NA);
    float mz = block_sum(pz, red, a) * (1.f / NA);
    px -= mx; py -= my; pz -= mz;
    float dx = px - nc[base + 0], dy = py - nc[base + 1], dz = pz - nc[base + 2];
    float s = block_sum(dx * dx + dy * dy + dz * dz, red, a);
    if (a == 0) lpart[b] = s;
}

__global__ void loss_final(const float* __restrict__ lpart, float* __restrict__ out)
{
    if (threadIdx.x == 0) {
        float s = 0.f;
        for (int i = 0; i < NB; i++) s += lpart[i];
        out[0] = s / (float)(NNODES * 3);
    }
}

// ---------------------------------------------------------------- launch
extern "C" void kernel_launch(void* const* d_in, const int* in_sizes, int n_in,
                              void* d_out, int out_size, void* d_ws, size_t ws_size,
                              hipStream_t stream)
{
    (void)in_sizes; (void)n_in; (void)out_size; (void)ws_size;
    const float* h     = (const float*)d_in[0];
    const float* x0    = (const float*)d_in[1];
    const float* noise = (const float*)d_in[2];
    const int*   t     = (const int*)d_in[3];
    const int*   row   = (const int*)d_in[4];
    const int*   col   = (const int*)d_in[5];
    const float* W_emb = (const float*)d_in[6];
    const float* b_emb = (const float*)d_in[7];
    const float* eW1   = (const float*)d_in[8];
    const float* eb1   = (const float*)d_in[9];
    const float* eW2   = (const float*)d_in[10];
    const float* eb2   = (const float*)d_in[11];
    const float* cW1   = (const float*)d_in[12];
    const float* cb1   = (const float*)d_in[13];
    const float* cW2   = (const float*)d_in[14];
    const float* nW1   = (const float*)d_in[15];
    const float* nb1   = (const float*)d_in[16];
    const float* nW2   = (const float*)d_in[17];
    const float* nb2   = (const float*)d_in[18];

    // ---- workspace layout (x_agg and m_i adjacent -> one memset per layer)
    float* f = (float*)d_ws;
    size_t fo = 0;
    float* temb    = f + fo; fo += NB * TEMBD;
    float* noise_c = f + fo; fo += NNODES * 3;
    float* xt      = f + fo; fo += NNODES * 3;
    float* x_cur   = f + fo; fo += NNODES * 3;
    float* x_agg   = f + fo; fo += NNODES * 3;
    float* m_i     = f + fo; fo += (size_t)NNODES * HID;
    float* lpart   = f + fo; fo += NB;
    float* msl0    = f + fo; fo += (size_t)NCHUNK * 256;
    float* msl1    = f + fo; fo += (size_t)NCHUNK * 256;
    float* xsl0    = f + fo; fo += (size_t)NCHUNK * 3;
    float* xsl1    = f + fo; fo += (size_t)NCHUNK * 3;

    int* iw = (int*)(f + fo);
    size_t io = 0;
    int* deg    = iw + io; io += NNODES;
    int* cursor = iw + io; io += NNODES;
    int* prow   = iw + io; io += NE;
    int* pcol   = iw + io; io += NE;
    int* tag0   = iw + io; io += NCHUNK;
    int* tag1   = iw + io; io += NCHUNK;

    size_t sbase_bytes = ((((char*)(iw + io)) - (char*)d_ws) + 15) & ~(size_t)15;
    short* sb = (short*)((char*)d_ws + sbase_bytes);
    short* wb  = sb;
    size_t so = W_TOTAL;
    short* hin = sb + so; so += (size_t)NNODES * 96;
    short* hh  = sb + so; so += (size_t)NNODES * HID;
    short* hh2 = sb + so; so += (size_t)NNODES * HID;
    short* P12 = sb + so; so += (size_t)NNODES * 512;

    // ---- prologue
    prep_kernel<<<NB, 256, 0, stream>>>(x0, noise, t, noise_c, xt, temb);
    hipMemsetAsync(deg, 0, NNODES * sizeof(int), stream);
    csr_hist<<<NE / 256, 256, 0, stream>>>(row, deg);
    csr_scan<<<1, 256, 0, stream>>>(deg, cursor);
    csr_scatter<<<NE / 256, 256, 0, stream>>>(row, col, cursor, prow, pcol);
    convert_weights<<<(W_TOTAL + 255) / 256, 256, 0, stream>>>(W_emb, eW1, eW2, cW1, nW1, nW2, wb);
    build_hin<<<(NNODES * 96) / 256, 256, 0, stream>>>(h, temb, hin);
    emb_p12_fused<<<NNODES / 16, 256, 0, stream>>>(
        hin, wb + WOFF_EMB, b_emb, wb + WOFF_L(0) + WOFF_AB, hh, P12);
    hipMemcpyAsync(x_cur, xt, (size_t)NNODES * 3 * sizeof(float), hipMemcpyDeviceToDevice, stream);

    short* hc = hh;
    short* hn = hh2;
    for (int l = 0; l < NL; l++) {
        const short* wl = wb + WOFF_L(l);
        hipMemsetAsync(x_agg, 0, (size_t)(NNODES * 3 + NNODES * HID) * sizeof(float), stream);
        egnn_edge_mfma<<<NE / 64, 256, 0, stream>>>(
            P12, x_cur, prow, pcol,
            eW1 + (size_t)l * 513 * 256 + 512 * 256, eb1 + (size_t)l * HID,
            wl + WOFF_E2, eb2 + (size_t)l * HID,
            wl + WOFF_C1, cb1 + (size_t)l * HID,
            cW2 + (size_t)l * HID,
            m_i, x_agg, msl0, msl1, xsl0, xsl1, tag0, tag1);
        reduce_scatter<<<NNODES, 256, 0, stream>>>(
            cursor, tag0, tag1, msl0, msl1, xsl0, xsl1, m_i, x_agg, x_cur);
        if (l < NL - 1) {
            node_p12_fused<<<NNODES / 16, 256, 0, stream>>>(
                hc, m_i,
                wl + WOFF_N1, nb1 + (size_t)l * HID,
                wl + WOFF_N2, nb2 + (size_t)l * HID,
                wb + WOFF_L(l + 1) + WOFF_AB,
                hn, P12);
            short* tmp = hc; hc = hn; hn = tmp;
        }
    }

    loss_part<<<NB, 256, 0, stream>>>(x_cur, xt, noise_c, lpart);
    loss_final<<<1, 64, 0, stream>>>(lpart, (float*)d_out);
}